// Round 5
// baseline (163.719 us; speedup 1.0000x reference)
//
#include <hip/hip_runtime.h>
#include <hip/hip_bf16.h>

using f32x4  = __attribute__((ext_vector_type(4))) float;
using bf16x8 = __attribute__((ext_vector_type(8))) __bf16;
using u16x8  = __attribute__((ext_vector_type(8))) unsigned short;

#define QSCALE 0.18033688f   // 0.125 * log2(e): scores pre-scaled into exp2 domain

static __device__ __forceinline__ unsigned short f2bf(float f) {
    unsigned u = __builtin_bit_cast(unsigned, f);
    u += 0x7FFF + ((u >> 16) & 1);   // RNE
    return (unsigned short)(u >> 16);
}

static __device__ __forceinline__ void gload_lds16(const unsigned short* g, unsigned short* l) {
    __builtin_amdgcn_global_load_lds(
        (const __attribute__((address_space(1))) unsigned int*)g,
        (__attribute__((address_space(3))) unsigned int*)l, 16, 0, 0);
}

// ---------------------------------------------------------------------------
// Kernel 0: fp32 -> bf16 convert (X q/k/v, W q/k/v).
// ---------------------------------------------------------------------------
__global__ __launch_bounds__(256) void cvt6(
    const float* __restrict__ s0, const float* __restrict__ s1, const float* __restrict__ s2,
    const float* __restrict__ s3, const float* __restrict__ s4, const float* __restrict__ s5,
    unsigned short* __restrict__ d0, unsigned short* __restrict__ d1, unsigned short* __restrict__ d2,
    unsigned short* __restrict__ d3, unsigned short* __restrict__ d4, unsigned short* __restrict__ d5)
{
    const int y = blockIdx.y;
    const float* s = y == 0 ? s0 : y == 1 ? s1 : y == 2 ? s2 : y == 3 ? s3 : y == 4 ? s4 : s5;
    unsigned short* d = y == 0 ? d0 : y == 1 ? d1 : y == 2 ? d2 : y == 3 ? d3 : y == 4 ? d4 : d5;
    const int n = (y < 3) ? 4 * 1024 * 1024 : 1024 * 1024;
    const int stride = gridDim.x * 256 * 8;
    for (int i = (blockIdx.x * 256 + threadIdx.x) * 8; i < n; i += stride) {
        f32x4 a = *(const f32x4*)(s + i);
        f32x4 b = *(const f32x4*)(s + i + 4);
        u16x8 o;
        o[0] = f2bf(a.x); o[1] = f2bf(a.y); o[2] = f2bf(a.z); o[3] = f2bf(a.w);
        o[4] = f2bf(b.x); o[5] = f2bf(b.y); o[6] = f2bf(b.z); o[7] = f2bf(b.w);
        *(u16x8*)(d + i) = o;
    }
}

// ---------------------------------------------------------------------------
// Kernel 1 (m97 structure): O[row][col] = A[row]·B[col] + bias, bf16.
// which = blockIdx.x>>8:
//   0: Q  = Xq·Wq^T  (M=4096,N=1024, bias[col], ×QSCALE)
//   1: K  = Xk·Wk^T  (M=4096,N=1024, bias[col])
//   2: Vt = Wv·Xv^T  (M=1024,N=4096, bias[row])  -> Vt[d][b*S+s]
// ---------------------------------------------------------------------------
__global__ __launch_bounds__(256) void gemm_bt(
    const unsigned short* __restrict__ A0, const unsigned short* __restrict__ A1, const unsigned short* __restrict__ A2,
    const unsigned short* __restrict__ B0, const unsigned short* __restrict__ B1, const unsigned short* __restrict__ B2,
    const float* __restrict__ b0, const float* __restrict__ b1, const float* __restrict__ b2,
    unsigned short* __restrict__ O0, unsigned short* __restrict__ O1, unsigned short* __restrict__ O2)
{
    const int K = 1024;
    const int idx = blockIdx.x;
    const int which = idx >> 8;
    const int local = idx & 255;
    const unsigned short* A = which == 0 ? A0 : (which == 1 ? A1 : A2);
    const unsigned short* B = which == 0 ? B0 : (which == 1 ? B1 : B2);
    const float* bias = which == 0 ? b0 : (which == 1 ? b1 : b2);
    unsigned short* O = which == 0 ? O0 : (which == 1 ? O1 : O2);

    const int bm = (which == 2) ? (local >> 5) : (local >> 3);
    const int bn = (which == 2) ? (local & 31) : (local & 7);
    const int Nst = (which == 2) ? 4096 : 1024;
    const int row0 = bm * 128, col0 = bn * 128;

    __shared__ __align__(16) unsigned short As[128 * 32];
    __shared__ __align__(16) unsigned short Bs[128 * 32];

    const int t = threadIdx.x;
    const int lane = t & 63;
    const int wave = t >> 6;
    const int wr = (wave >> 1) * 64, wc = (wave & 1) * 64;
    const int fr = lane & 15;
    const int fq = lane >> 4;

    f32x4 acc[4][4] = {};

    const int r0s = t >> 2, k0s = (t & 3) * 8;
    const int r1s = (t + 256) >> 2, k1s = (t & 3) * 8;
    unsigned short* ldsA0 = &As[(wave * 64) * 8];
    unsigned short* ldsA1 = &As[(256 + wave * 64) * 8];
    unsigned short* ldsB0 = &Bs[(wave * 64) * 8];
    unsigned short* ldsB1 = &Bs[(256 + wave * 64) * 8];

    for (int k0 = 0; k0 < K; k0 += 32) {
        gload_lds16(A + (size_t)(row0 + r0s) * K + k0 + k0s, ldsA0);
        gload_lds16(A + (size_t)(row0 + r1s) * K + k0 + k1s, ldsA1);
        gload_lds16(B + (size_t)(col0 + r0s) * K + k0 + k0s, ldsB0);
        gload_lds16(B + (size_t)(col0 + r1s) * K + k0 + k1s, ldsB1);
        __syncthreads();

        bf16x8 af[4], bfr[4];
        #pragma unroll
        for (int m = 0; m < 4; ++m)
            af[m] = *(const bf16x8*)(&As[(wr + m * 16 + fr) * 32 + fq * 8]);
        #pragma unroll
        for (int n = 0; n < 4; ++n)
            bfr[n] = *(const bf16x8*)(&Bs[(wc + n * 16 + fr) * 32 + fq * 8]);
        #pragma unroll
        for (int m = 0; m < 4; ++m)
            #pragma unroll
            for (int n = 0; n < 4; ++n)
                acc[m][n] = __builtin_amdgcn_mfma_f32_16x16x32_bf16(af[m], bfr[n], acc[m][n], 0, 0, 0);
        __syncthreads();
    }

    if (which == 2) {
        // bias on row (d-dim), no scale
        #pragma unroll
        for (int m = 0; m < 4; ++m) {
            #pragma unroll
            for (int r = 0; r < 4; ++r) {
                const int row = row0 + wr + m * 16 + fq * 4 + r;
                const float bv = bias[row];
                #pragma unroll
                for (int n = 0; n < 4; ++n) {
                    const int col = col0 + wc + n * 16 + fr;
                    O[(size_t)row * Nst + col] = f2bf(acc[m][n][r] + bv);
                }
            }
        }
    } else {
        const float sc = (which == 0) ? QSCALE : 1.0f;
        #pragma unroll
        for (int n = 0; n < 4; ++n) {
            const int col = col0 + wc + n * 16 + fr;
            const float bv = bias[col];
            #pragma unroll
            for (int m = 0; m < 4; ++m) {
                #pragma unroll
                for (int r = 0; r < 4; ++r) {
                    const int row = row0 + wr + m * 16 + fq * 4 + r;
                    O[(size_t)row * Nst + col] = f2bf((acc[m][n][r] + bv) * sc);
                }
            }
        }
    }
}

// ---------------------------------------------------------------------------
// Kernel 2: causal flash attention, barrier-free. 1024 blocks (one 64-row
// q-block each), XCD-swizzled so each (b,h)'s 16 blocks share one XCD's L2.
// K and V fragments read directly from global (L2-resident); only the
// per-wave P re-layout buffer lives in LDS. Scores pre-scaled (exp2 domain).
// ---------------------------------------------------------------------------
__global__ __launch_bounds__(256) void attn_fwd(
    const unsigned short* __restrict__ Qw, const unsigned short* __restrict__ Kw,
    const unsigned short* __restrict__ Vt, const int* __restrict__ amask,
    float* __restrict__ out)
{
    const int S = 1024, Dm = 1024;
    const int wg = blockIdx.x;
    const int bh = (wg & 7) | ((wg >> 7) << 3);   // all 16 q-blocks of a bh -> same XCD
    const int qb = (wg >> 3) & 15;
    const int b = bh >> 4, h = bh & 15;
    const int t = threadIdx.x, lane = t & 63, wave = t >> 6;
    const int fr = lane & 15, fq = lane >> 4;

    __shared__ __align__(16) unsigned short Ps[4][16][72];

    const int q0 = qb * 64;
    const size_t kwbase = (size_t)(b * S) * Dm + h * 64;
    const size_t vtbase = (size_t)(h * 64) * 4096 + b * 1024;   // Vt[d][b*S+s]

    const int qrowA = q0 + wave * 16 + fr;
    const size_t qbp = (size_t)(b * S + qrowA) * Dm + h * 64;
    const bf16x8 qf0 = *(const bf16x8*)(Qw + qbp + fq * 8);
    const bf16x8 qf1 = *(const bf16x8*)(Qw + qbp + 32 + fq * 8);

    f32x4 oacc[4] = {};
    float mrow[4], lpart[4];
    #pragma unroll
    for (int r = 0; r < 4; ++r) { mrow[r] = -3.0e38f; lpart[r] = 0.f; }

    const int nkt = qb + 1;
    for (int kt = 0; kt < nkt; ++kt) {
        const int k0 = kt * 64;

        // V fragments direct from global (issue early)
        bf16x8 vb[4][2];
        #pragma unroll
        for (int d = 0; d < 4; ++d)
            #pragma unroll
            for (int kc = 0; kc < 2; ++kc)
                vb[d][kc] = *(const bf16x8*)(Vt + vtbase + (size_t)(d * 16 + fr) * 4096 + k0 + kc * 32 + fq * 8);

        // S = Q K^T, K fragments direct from global
        f32x4 sfr[4];
        __builtin_amdgcn_s_setprio(1);
        #pragma unroll
        for (int nf = 0; nf < 4; ++nf) {
            const unsigned short* kp = Kw + kwbase + (size_t)(k0 + nf * 16 + fr) * Dm;
            const bf16x8 kb0 = *(const bf16x8*)(kp + fq * 8);
            const bf16x8 kb1 = *(const bf16x8*)(kp + 32 + fq * 8);
            f32x4 z = {};
            z = __builtin_amdgcn_mfma_f32_16x16x32_bf16(qf0, kb0, z, 0, 0, 0);
            z = __builtin_amdgcn_mfma_f32_16x16x32_bf16(qf1, kb1, z, 0, 0, 0);
            sfr[nf] = z;
        }
        __builtin_amdgcn_s_setprio(0);

        // att_mask (fast path: all ones)
        const int mk = amask[b * S + k0 + lane];
        if (!__all(mk != 0)) {
            #pragma unroll
            for (int nf = 0; nf < 4; ++nf) {
                const float pen = (amask[b * S + k0 + nf * 16 + fr] == 0) ? -3.0e38f : 0.f;
                #pragma unroll
                for (int r = 0; r < 4; ++r) sfr[nf][r] += pen;
            }
        }
        // causal: only diagonal tile
        if (kt == nkt - 1) {
            #pragma unroll
            for (int nf = 0; nf < 4; ++nf) {
                const int kpos = k0 + nf * 16 + fr;
                #pragma unroll
                for (int r = 0; r < 4; ++r) {
                    const int qr = q0 + wave * 16 + fq * 4 + r;
                    if (kpos > qr) sfr[nf][r] = -3.0e38f;
                }
            }
        }

        // defer-max
        float plm[4];
        #pragma unroll
        for (int r = 0; r < 4; ++r)
            plm[r] = fmaxf(fmaxf(sfr[0][r], sfr[1][r]), fmaxf(sfr[2][r], sfr[3][r]));
        float grow = plm[0] - mrow[0];
        #pragma unroll
        for (int r = 1; r < 4; ++r) grow = fmaxf(grow, plm[r] - mrow[r]);
        if (!__all(grow <= 8.0f)) {
            #pragma unroll
            for (int r = 0; r < 4; ++r) {
                float v = plm[r];
                v = fmaxf(v, __shfl_xor(v, 1));
                v = fmaxf(v, __shfl_xor(v, 2));
                v = fmaxf(v, __shfl_xor(v, 4));
                v = fmaxf(v, __shfl_xor(v, 8));
                const float mn = fmaxf(mrow[r], v);
                const float sc = exp2f(mrow[r] - mn);
                mrow[r] = mn;
                lpart[r] *= sc;
                #pragma unroll
                for (int d = 0; d < 4; ++d) oacc[d][r] *= sc;
            }
        }

        // p = exp2(s - m); per-lane partial sums; P -> per-wave LDS (bf16)
        #pragma unroll
        for (int nf = 0; nf < 4; ++nf) {
            #pragma unroll
            for (int r = 0; r < 4; ++r) {
                const float p = exp2f(sfr[nf][r] - mrow[r]);
                lpart[r] += p;
                Ps[wave][fq * 4 + r][nf * 16 + fr] = f2bf(p);
            }
        }

        // O += P V
        const bf16x8 pa0 = *(const bf16x8*)(&Ps[wave][fr][fq * 8]);
        const bf16x8 pa1 = *(const bf16x8*)(&Ps[wave][fr][32 + fq * 8]);
        __builtin_amdgcn_s_setprio(1);
        #pragma unroll
        for (int d = 0; d < 4; ++d) {
            oacc[d] = __builtin_amdgcn_mfma_f32_16x16x32_bf16(pa0, vb[d][0], oacc[d], 0, 0, 0);
            oacc[d] = __builtin_amdgcn_mfma_f32_16x16x32_bf16(pa1, vb[d][1], oacc[d], 0, 0, 0);
        }
        __builtin_amdgcn_s_setprio(0);
    }

    // epilogue
    float inv[4];
    #pragma unroll
    for (int r = 0; r < 4; ++r) {
        float v = lpart[r];
        v += __shfl_xor(v, 1);
        v += __shfl_xor(v, 2);
        v += __shfl_xor(v, 4);
        v += __shfl_xor(v, 8);
        inv[r] = 1.0f / v;
    }
    #pragma unroll
    for (int d = 0; d < 4; ++d)
        #pragma unroll
        for (int r = 0; r < 4; ++r) {
            const int qr = q0 + wave * 16 + fq * 4 + r;
            out[(size_t)(b * S + qr) * Dm + h * 64 + d * 16 + fr] = oacc[d][r] * inv[r];
        }
}

// ---------------------------------------------------------------------------
extern "C" void kernel_launch(void* const* d_in, const int* in_sizes, int n_in,
                              void* d_out, int out_size, void* d_ws, size_t ws_size,
                              hipStream_t stream)
{
    const float* query = (const float*)d_in[0];
    const float* key_  = (const float*)d_in[1];
    const float* value = (const float*)d_in[2];
    const int*   amask = (const int*)d_in[3];
    const float* Wq = (const float*)d_in[4];
    const float* bq = (const float*)d_in[5];
    const float* Wk = (const float*)d_in[6];
    const float* bk = (const float*)d_in[7];
    const float* Wv = (const float*)d_in[8];
    const float* bv = (const float*)d_in[9];
    float* out = (float*)d_out;

    const size_t MD = (size_t)4096 * 1024;
    const size_t WD = (size_t)1024 * 1024;
    unsigned short* Qw  = (unsigned short*)d_ws;
    unsigned short* Kw  = Qw + MD;
    unsigned short* Vtw = Kw + MD;     // [1024][4096]
    unsigned short* Xq  = Vtw + MD;
    unsigned short* Xk  = Xq + MD;
    unsigned short* Xv  = Xk + MD;
    unsigned short* Wqb = Xv + MD;
    unsigned short* Wkb = Wqb + WD;
    unsigned short* Wvb = Wkb + WD;

    hipLaunchKernelGGL(cvt6, dim3(512, 6), dim3(256), 0, stream,
                       query, key_, value, Wq, Wk, Wv,
                       Xq, Xk, Xv, Wqb, Wkb, Wvb);
    // which 0: Q = Xq·Wq^T; 1: K = Xk·Wk^T; 2: Vt = Wv·Xv^T
    hipLaunchKernelGGL(gemm_bt, dim3(768), dim3(256), 0, stream,
                       Xq, Xk, Wvb, Wqb, Wkb, Xv, bq, bk, bv, Qw, Kw, Vtw);
    hipLaunchKernelGGL(attn_fwd, dim3(1024), dim3(256), 0, stream,
                       Qw, Kw, Vtw, amask, out);
}

// Round 6
// 123.353 us; speedup vs baseline: 1.3272x; 1.3272x over previous
//
#include <hip/hip_runtime.h>
#include <hip/hip_bf16.h>

using f32x4  = __attribute__((ext_vector_type(4))) float;
using bf16x8 = __attribute__((ext_vector_type(8))) __bf16;
using u16x8  = __attribute__((ext_vector_type(8))) unsigned short;

#define QSCALE 0.18033688f   // 0.125 * log2(e): scores pre-scaled into exp2 domain

static __device__ __forceinline__ unsigned short f2bf(float f) {
    unsigned u = __builtin_bit_cast(unsigned, f);
    u += 0x7FFF + ((u >> 16) & 1);   // RNE
    return (unsigned short)(u >> 16);
}

static __device__ __forceinline__ void gload_lds16(const unsigned short* g, unsigned short* l) {
    __builtin_amdgcn_global_load_lds(
        (const __attribute__((address_space(1))) unsigned int*)g,
        (__attribute__((address_space(3))) unsigned int*)l, 16, 0, 0);
}

// ---------------------------------------------------------------------------
// Kernel 0: fp32 -> bf16 convert (X q/k/v, W q/k/v).
// ---------------------------------------------------------------------------
__global__ __launch_bounds__(256) void cvt6(
    const float* __restrict__ s0, const float* __restrict__ s1, const float* __restrict__ s2,
    const float* __restrict__ s3, const float* __restrict__ s4, const float* __restrict__ s5,
    unsigned short* __restrict__ d0, unsigned short* __restrict__ d1, unsigned short* __restrict__ d2,
    unsigned short* __restrict__ d3, unsigned short* __restrict__ d4, unsigned short* __restrict__ d5)
{
    const int y = blockIdx.y;
    const float* s = y == 0 ? s0 : y == 1 ? s1 : y == 2 ? s2 : y == 3 ? s3 : y == 4 ? s4 : s5;
    unsigned short* d = y == 0 ? d0 : y == 1 ? d1 : y == 2 ? d2 : y == 3 ? d3 : y == 4 ? d4 : d5;
    const int n = (y < 3) ? 4 * 1024 * 1024 : 1024 * 1024;
    const int stride = gridDim.x * 256 * 8;
    for (int i = (blockIdx.x * 256 + threadIdx.x) * 8; i < n; i += stride) {
        f32x4 a = *(const f32x4*)(s + i);
        f32x4 b = *(const f32x4*)(s + i + 4);
        u16x8 o;
        o[0] = f2bf(a.x); o[1] = f2bf(a.y); o[2] = f2bf(a.z); o[3] = f2bf(a.w);
        o[4] = f2bf(b.x); o[5] = f2bf(b.y); o[6] = f2bf(b.z); o[7] = f2bf(b.w);
        *(u16x8*)(d + i) = o;
    }
}

// ---------------------------------------------------------------------------
// Kernel 1 (m97 structure): O[row][col] = A[row]·B[col] + bias, bf16.
// which = blockIdx.x>>8:
//   0: Q  = Xq·Wq^T  (M=4096,N=1024, bias[col], ×QSCALE)
//   1: K  = Xk·Wk^T  (M=4096,N=1024, bias[col])
//   2: Vt = Wv·Xv^T  (M=1024,N=4096, bias[row])  -> Vt[d][b*S+s]
// ---------------------------------------------------------------------------
__global__ __launch_bounds__(256) void gemm_bt(
    const unsigned short* __restrict__ A0, const unsigned short* __restrict__ A1, const unsigned short* __restrict__ A2,
    const unsigned short* __restrict__ B0, const unsigned short* __restrict__ B1, const unsigned short* __restrict__ B2,
    const float* __restrict__ b0, const float* __restrict__ b1, const float* __restrict__ b2,
    unsigned short* __restrict__ O0, unsigned short* __restrict__ O1, unsigned short* __restrict__ O2)
{
    const int K = 1024;
    const int idx = blockIdx.x;
    const int which = idx >> 8;
    const int local = idx & 255;
    const unsigned short* A = which == 0 ? A0 : (which == 1 ? A1 : A2);
    const unsigned short* B = which == 0 ? B0 : (which == 1 ? B1 : B2);
    const float* bias = which == 0 ? b0 : (which == 1 ? b1 : b2);
    unsigned short* O = which == 0 ? O0 : (which == 1 ? O1 : O2);

    const int bm = (which == 2) ? (local >> 5) : (local >> 3);
    const int bn = (which == 2) ? (local & 31) : (local & 7);
    const int Nst = (which == 2) ? 4096 : 1024;
    const int row0 = bm * 128, col0 = bn * 128;

    __shared__ __align__(16) unsigned short As[128 * 32];
    __shared__ __align__(16) unsigned short Bs[128 * 32];

    const int t = threadIdx.x;
    const int lane = t & 63;
    const int wave = t >> 6;
    const int wr = (wave >> 1) * 64, wc = (wave & 1) * 64;
    const int fr = lane & 15;
    const int fq = lane >> 4;

    f32x4 acc[4][4] = {};

    const int r0s = t >> 2, k0s = (t & 3) * 8;
    const int r1s = (t + 256) >> 2, k1s = (t & 3) * 8;
    unsigned short* ldsA0 = &As[(wave * 64) * 8];
    unsigned short* ldsA1 = &As[(256 + wave * 64) * 8];
    unsigned short* ldsB0 = &Bs[(wave * 64) * 8];
    unsigned short* ldsB1 = &Bs[(256 + wave * 64) * 8];

    for (int k0 = 0; k0 < K; k0 += 32) {
        gload_lds16(A + (size_t)(row0 + r0s) * K + k0 + k0s, ldsA0);
        gload_lds16(A + (size_t)(row0 + r1s) * K + k0 + k1s, ldsA1);
        gload_lds16(B + (size_t)(col0 + r0s) * K + k0 + k0s, ldsB0);
        gload_lds16(B + (size_t)(col0 + r1s) * K + k0 + k1s, ldsB1);
        __syncthreads();

        bf16x8 af[4], bfr[4];
        #pragma unroll
        for (int m = 0; m < 4; ++m)
            af[m] = *(const bf16x8*)(&As[(wr + m * 16 + fr) * 32 + fq * 8]);
        #pragma unroll
        for (int n = 0; n < 4; ++n)
            bfr[n] = *(const bf16x8*)(&Bs[(wc + n * 16 + fr) * 32 + fq * 8]);
        #pragma unroll
        for (int m = 0; m < 4; ++m)
            #pragma unroll
            for (int n = 0; n < 4; ++n)
                acc[m][n] = __builtin_amdgcn_mfma_f32_16x16x32_bf16(af[m], bfr[n], acc[m][n], 0, 0, 0);
        __syncthreads();
    }

    if (which == 2) {
        #pragma unroll
        for (int m = 0; m < 4; ++m) {
            #pragma unroll
            for (int r = 0; r < 4; ++r) {
                const int row = row0 + wr + m * 16 + fq * 4 + r;
                const float bv = bias[row];
                #pragma unroll
                for (int n = 0; n < 4; ++n) {
                    const int col = col0 + wc + n * 16 + fr;
                    O[(size_t)row * Nst + col] = f2bf(acc[m][n][r] + bv);
                }
            }
        }
    } else {
        const float sc = (which == 0) ? QSCALE : 1.0f;
        #pragma unroll
        for (int n = 0; n < 4; ++n) {
            const int col = col0 + wc + n * 16 + fr;
            const float bv = bias[col];
            #pragma unroll
            for (int m = 0; m < 4; ++m) {
                #pragma unroll
                for (int r = 0; r < 4; ++r) {
                    const int row = row0 + wr + m * 16 + fq * 4 + r;
                    O[(size_t)row * Nst + col] = f2bf((acc[m][n][r] + bv) * sc);
                }
            }
        }
    }
}

// ---------------------------------------------------------------------------
// Kernel 2: causal flash attention. 1024 blocks (one 64-row q-block each),
// XCD-swizzled. K double-buffered in LDS via global_load_lds (linear dest,
// XOR-swizzled pre-permuted global source; read side applies same XOR ->
// conflict-free ds_read_b128). One barrier per k-tile; staging of tile t+1
// hides under tile t's compute. V fragments direct from global Vt (L2-hot).
// ---------------------------------------------------------------------------
__global__ __launch_bounds__(256) void attn_fwd(
    const unsigned short* __restrict__ Qw, const unsigned short* __restrict__ Kw,
    const unsigned short* __restrict__ Vt, const int* __restrict__ amask,
    float* __restrict__ out)
{
    const int S = 1024, Dm = 1024;
    const int wg = blockIdx.x;
    const int bh = (wg & 7) | ((wg >> 7) << 3);   // all 16 q-blocks of a bh -> same XCD
    const int qb = (wg >> 3) & 15;
    const int b = bh >> 4, h = bh & 15;
    const int t = threadIdx.x, lane = t & 63, wave = t >> 6;
    const int fr = lane & 15, fq = lane >> 4;

    __shared__ __align__(16) unsigned short Ks[2][4096];   // [64 rows][64 cols], XOR-swizzled chunks
    __shared__ __align__(16) unsigned short Ps[4][16][72];

    const int q0 = qb * 64;
    const size_t kwbase = (size_t)(b * S) * Dm + h * 64;
    const size_t vtbase = (size_t)(h * 64) * 4096 + b * 1024;   // Vt[d][b*S+s]

    // staging geometry: call s covers rows [32s,32s+32); thread -> (row, chunk)
    const int srow = t >> 3, schunk = t & 7;
    const int wbase = wave * 512;            // u16 offset of this wave's 1KB segment

    const int qrowA = q0 + wave * 16 + fr;
    const size_t qbp = (size_t)(b * S + qrowA) * Dm + h * 64;
    const bf16x8 qf0 = *(const bf16x8*)(Qw + qbp + fq * 8);
    const bf16x8 qf1 = *(const bf16x8*)(Qw + qbp + 32 + fq * 8);

    f32x4 oacc[4] = {};
    float mrow[4], lpart[4];
    #pragma unroll
    for (int r = 0; r < 4; ++r) { mrow[r] = -3.0e38f; lpart[r] = 0.f; }

    const int nkt = qb + 1;

    // prologue: stage tile 0 into buf 0
    #pragma unroll
    for (int s = 0; s < 2; ++s) {
        const int r = srow + 32 * s;
        const int cc = schunk ^ (r & 7);
        gload_lds16(Kw + kwbase + (size_t)r * Dm + cc * 8, &Ks[0][s * 2048 + wbase]);
    }
    __syncthreads();

    int cur = 0;
    for (int kt = 0; kt < nkt; ++kt) {
        const int k0 = kt * 64;

        // stage next K tile into the other buffer (async, drains at barrier)
        if (kt + 1 < nkt) {
            #pragma unroll
            for (int s = 0; s < 2; ++s) {
                const int r = srow + 32 * s;
                const int cc = schunk ^ (r & 7);
                gload_lds16(Kw + kwbase + (size_t)(k0 + 64 + r) * Dm + cc * 8,
                            &Ks[cur ^ 1][s * 2048 + wbase]);
            }
        }

        // V fragments direct from global (issue early, consumed by PV)
        bf16x8 vb[4][2];
        #pragma unroll
        for (int d = 0; d < 4; ++d)
            #pragma unroll
            for (int kc = 0; kc < 2; ++kc)
                vb[d][kc] = *(const bf16x8*)(Vt + vtbase + (size_t)(d * 16 + fr) * 4096 + k0 + kc * 32 + fq * 8);

        // S = Q K^T from swizzled LDS
        f32x4 sfr[4];
        __builtin_amdgcn_s_setprio(1);
        #pragma unroll
        for (int nf = 0; nf < 4; ++nf) {
            const int row = nf * 16 + fr;
            const bf16x8 kb0 = *(const bf16x8*)(&Ks[cur][row * 64 + ((fq ^ (row & 7)) * 8)]);
            const bf16x8 kb1 = *(const bf16x8*)(&Ks[cur][row * 64 + (((fq + 4) ^ (row & 7)) * 8)]);
            f32x4 z = {};
            z = __builtin_amdgcn_mfma_f32_16x16x32_bf16(qf0, kb0, z, 0, 0, 0);
            z = __builtin_amdgcn_mfma_f32_16x16x32_bf16(qf1, kb1, z, 0, 0, 0);
            sfr[nf] = z;
        }
        __builtin_amdgcn_s_setprio(0);

        // att_mask (fast path: all ones)
        const int mk = amask[b * S + k0 + lane];
        if (!__all(mk != 0)) {
            #pragma unroll
            for (int nf = 0; nf < 4; ++nf) {
                const float pen = (amask[b * S + k0 + nf * 16 + fr] == 0) ? -3.0e38f : 0.f;
                #pragma unroll
                for (int r = 0; r < 4; ++r) sfr[nf][r] += pen;
            }
        }
        // causal: only diagonal tile
        if (kt == nkt - 1) {
            #pragma unroll
            for (int nf = 0; nf < 4; ++nf) {
                const int kpos = k0 + nf * 16 + fr;
                #pragma unroll
                for (int r = 0; r < 4; ++r) {
                    const int qr = q0 + wave * 16 + fq * 4 + r;
                    if (kpos > qr) sfr[nf][r] = -3.0e38f;
                }
            }
        }

        // defer-max (THR=8 in exp2 domain)
        float plm[4];
        #pragma unroll
        for (int r = 0; r < 4; ++r)
            plm[r] = fmaxf(fmaxf(sfr[0][r], sfr[1][r]), fmaxf(sfr[2][r], sfr[3][r]));
        float grow = plm[0] - mrow[0];
        #pragma unroll
        for (int r = 1; r < 4; ++r) grow = fmaxf(grow, plm[r] - mrow[r]);
        if (!__all(grow <= 8.0f)) {
            #pragma unroll
            for (int r = 0; r < 4; ++r) {
                float v = plm[r];
                v = fmaxf(v, __shfl_xor(v, 1));
                v = fmaxf(v, __shfl_xor(v, 2));
                v = fmaxf(v, __shfl_xor(v, 4));
                v = fmaxf(v, __shfl_xor(v, 8));
                const float mn = fmaxf(mrow[r], v);
                const float sc = exp2f(mrow[r] - mn);
                mrow[r] = mn;
                lpart[r] *= sc;
                #pragma unroll
                for (int d = 0; d < 4; ++d) oacc[d][r] *= sc;
            }
        }

        // p = exp2(s - m); per-lane partial sums; P -> per-wave LDS (bf16)
        #pragma unroll
        for (int nf = 0; nf < 4; ++nf) {
            #pragma unroll
            for (int r = 0; r < 4; ++r) {
                const float p = exp2f(sfr[nf][r] - mrow[r]);
                lpart[r] += p;
                Ps[wave][fq * 4 + r][nf * 16 + fr] = f2bf(p);
            }
        }

        // O += P V
        const bf16x8 pa0 = *(const bf16x8*)(&Ps[wave][fr][fq * 8]);
        const bf16x8 pa1 = *(const bf16x8*)(&Ps[wave][fr][32 + fq * 8]);
        __builtin_amdgcn_s_setprio(1);
        #pragma unroll
        for (int d = 0; d < 4; ++d) {
            oacc[d] = __builtin_amdgcn_mfma_f32_16x16x32_bf16(pa0, vb[d][0], oacc[d], 0, 0, 0);
            oacc[d] = __builtin_amdgcn_mfma_f32_16x16x32_bf16(pa1, vb[d][1], oacc[d], 0, 0, 0);
        }
        __builtin_amdgcn_s_setprio(0);

        __syncthreads();   // drains next-tile staging; releases buffers
        cur ^= 1;
    }

    // epilogue
    float inv[4];
    #pragma unroll
    for (int r = 0; r < 4; ++r) {
        float v = lpart[r];
        v += __shfl_xor(v, 1);
        v += __shfl_xor(v, 2);
        v += __shfl_xor(v, 4);
        v += __shfl_xor(v, 8);
        inv[r] = 1.0f / v;
    }
    #pragma unroll
    for (int d = 0; d < 4; ++d)
        #pragma unroll
        for (int r = 0; r < 4; ++r) {
            const int qr = q0 + wave * 16 + fq * 4 + r;
            out[(size_t)(b * S + qr) * Dm + h * 64 + d * 16 + fr] = oacc[d][r] * inv[r];
        }
}

// ---------------------------------------------------------------------------
extern "C" void kernel_launch(void* const* d_in, const int* in_sizes, int n_in,
                              void* d_out, int out_size, void* d_ws, size_t ws_size,
                              hipStream_t stream)
{
    const float* query = (const float*)d_in[0];
    const float* key_  = (const float*)d_in[1];
    const float* value = (const float*)d_in[2];
    const int*   amask = (const int*)d_in[3];
    const float* Wq = (const float*)d_in[4];
    const float* bq = (const float*)d_in[5];
    const float* Wk = (const float*)d_in[6];
    const float* bk = (const float*)d_in[7];
    const float* Wv = (const float*)d_in[8];
    const float* bv = (const float*)d_in[9];
    float* out = (float*)d_out;

    const size_t MD = (size_t)4096 * 1024;
    const size_t WD = (size_t)1024 * 1024;
    unsigned short* Qw  = (unsigned short*)d_ws;
    unsigned short* Kw  = Qw + MD;
    unsigned short* Vtw = Kw + MD;     // [1024][4096]
    unsigned short* Xq  = Vtw + MD;
    unsigned short* Xk  = Xq + MD;
    unsigned short* Xv  = Xk + MD;
    unsigned short* Wqb = Xv + MD;
    unsigned short* Wkb = Wqb + WD;
    unsigned short* Wvb = Wkb + WD;

    hipLaunchKernelGGL(cvt6, dim3(512, 6), dim3(256), 0, stream,
                       query, key_, value, Wq, Wk, Wv,
                       Xq, Xk, Xv, Wqb, Wkb, Wvb);
    // which 0: Q = Xq·Wq^T; 1: K = Xk·Wk^T; 2: Vt = Wv·Xv^T
    hipLaunchKernelGGL(gemm_bt, dim3(768), dim3(256), 0, stream,
                       Xq, Xk, Wvb, Wqb, Wkb, Xv, bq, bk, bv, Qw, Kw, Vtw);
    hipLaunchKernelGGL(attn_fwd, dim3(1024), dim3(256), 0, stream,
                       Qw, Kw, Vtw, amask, out);
}

// Round 7
// 114.551 us; speedup vs baseline: 1.4292x; 1.0768x over previous
//
#include <hip/hip_runtime.h>
#include <hip/hip_bf16.h>

using f32x4  = __attribute__((ext_vector_type(4))) float;
using bf16x8 = __attribute__((ext_vector_type(8))) __bf16;
using u16x8  = __attribute__((ext_vector_type(8))) unsigned short;

#define QSCALE 0.18033688f   // 0.125 * log2(e): scores pre-scaled into exp2 domain

static __device__ __forceinline__ unsigned short f2bf(float f) {
    unsigned u = __builtin_bit_cast(unsigned, f);
    u += 0x7FFF + ((u >> 16) & 1);   // RNE
    return (unsigned short)(u >> 16);
}

static __device__ __forceinline__ void gload_lds16(const unsigned short* g, unsigned short* l) {
    __builtin_amdgcn_global_load_lds(
        (const __attribute__((address_space(1))) unsigned int*)g,
        (__attribute__((address_space(3))) unsigned int*)l, 16, 0, 0);
}

// ---------------------------------------------------------------------------
// Kernel 0: fp32 -> bf16 convert (X q/k/v, W q/k/v).
// ---------------------------------------------------------------------------
__global__ __launch_bounds__(256) void cvt6(
    const float* __restrict__ s0, const float* __restrict__ s1, const float* __restrict__ s2,
    const float* __restrict__ s3, const float* __restrict__ s4, const float* __restrict__ s5,
    unsigned short* __restrict__ d0, unsigned short* __restrict__ d1, unsigned short* __restrict__ d2,
    unsigned short* __restrict__ d3, unsigned short* __restrict__ d4, unsigned short* __restrict__ d5)
{
    const int y = blockIdx.y;
    const float* s = y == 0 ? s0 : y == 1 ? s1 : y == 2 ? s2 : y == 3 ? s3 : y == 4 ? s4 : s5;
    unsigned short* d = y == 0 ? d0 : y == 1 ? d1 : y == 2 ? d2 : y == 3 ? d3 : y == 4 ? d4 : d5;
    const int n = (y < 3) ? 4 * 1024 * 1024 : 1024 * 1024;
    const int stride = gridDim.x * 256 * 8;
    for (int i = (blockIdx.x * 256 + threadIdx.x) * 8; i < n; i += stride) {
        f32x4 a = *(const f32x4*)(s + i);
        f32x4 b = *(const f32x4*)(s + i + 4);
        u16x8 o;
        o[0] = f2bf(a.x); o[1] = f2bf(a.y); o[2] = f2bf(a.z); o[3] = f2bf(a.w);
        o[4] = f2bf(b.x); o[5] = f2bf(b.y); o[6] = f2bf(b.z); o[7] = f2bf(b.w);
        *(u16x8*)(d + i) = o;
    }
}

// ---------------------------------------------------------------------------
// Kernel 1 (m97 structure): O[row][col] = A[row]·B[col] + bias, bf16.
// which = blockIdx.x>>8:
//   0: Q  = Xq·Wq^T  (M=4096,N=1024, bias[col], ×QSCALE)
//   1: K  = Xk·Wk^T  (M=4096,N=1024, bias[col])
//   2: Vt = Wv·Xv^T  (M=1024,N=4096, bias[row])  -> Vt[d][b*S+s]
// ---------------------------------------------------------------------------
__global__ __launch_bounds__(256) void gemm_bt(
    const unsigned short* __restrict__ A0, const unsigned short* __restrict__ A1, const unsigned short* __restrict__ A2,
    const unsigned short* __restrict__ B0, const unsigned short* __restrict__ B1, const unsigned short* __restrict__ B2,
    const float* __restrict__ b0, const float* __restrict__ b1, const float* __restrict__ b2,
    unsigned short* __restrict__ O0, unsigned short* __restrict__ O1, unsigned short* __restrict__ O2)
{
    const int K = 1024;
    const int idx = blockIdx.x;
    const int which = idx >> 8;
    const int local = idx & 255;
    const unsigned short* A = which == 0 ? A0 : (which == 1 ? A1 : A2);
    const unsigned short* B = which == 0 ? B0 : (which == 1 ? B1 : B2);
    const float* bias = which == 0 ? b0 : (which == 1 ? b1 : b2);
    unsigned short* O = which == 0 ? O0 : (which == 1 ? O1 : O2);

    const int bm = (which == 2) ? (local >> 5) : (local >> 3);
    const int bn = (which == 2) ? (local & 31) : (local & 7);
    const int Nst = (which == 2) ? 4096 : 1024;
    const int row0 = bm * 128, col0 = bn * 128;

    __shared__ __align__(16) unsigned short As[128 * 32];
    __shared__ __align__(16) unsigned short Bs[128 * 32];

    const int t = threadIdx.x;
    const int lane = t & 63;
    const int wave = t >> 6;
    const int wr = (wave >> 1) * 64, wc = (wave & 1) * 64;
    const int fr = lane & 15;
    const int fq = lane >> 4;

    f32x4 acc[4][4] = {};

    const int r0s = t >> 2, k0s = (t & 3) * 8;
    const int r1s = (t + 256) >> 2, k1s = (t & 3) * 8;
    unsigned short* ldsA0 = &As[(wave * 64) * 8];
    unsigned short* ldsA1 = &As[(256 + wave * 64) * 8];
    unsigned short* ldsB0 = &Bs[(wave * 64) * 8];
    unsigned short* ldsB1 = &Bs[(256 + wave * 64) * 8];

    for (int k0 = 0; k0 < K; k0 += 32) {
        gload_lds16(A + (size_t)(row0 + r0s) * K + k0 + k0s, ldsA0);
        gload_lds16(A + (size_t)(row0 + r1s) * K + k0 + k1s, ldsA1);
        gload_lds16(B + (size_t)(col0 + r0s) * K + k0 + k0s, ldsB0);
        gload_lds16(B + (size_t)(col0 + r1s) * K + k0 + k1s, ldsB1);
        __syncthreads();

        bf16x8 af[4], bfr[4];
        #pragma unroll
        for (int m = 0; m < 4; ++m)
            af[m] = *(const bf16x8*)(&As[(wr + m * 16 + fr) * 32 + fq * 8]);
        #pragma unroll
        for (int n = 0; n < 4; ++n)
            bfr[n] = *(const bf16x8*)(&Bs[(wc + n * 16 + fr) * 32 + fq * 8]);
        #pragma unroll
        for (int m = 0; m < 4; ++m)
            #pragma unroll
            for (int n = 0; n < 4; ++n)
                acc[m][n] = __builtin_amdgcn_mfma_f32_16x16x32_bf16(af[m], bfr[n], acc[m][n], 0, 0, 0);
        __syncthreads();
    }

    if (which == 2) {
        #pragma unroll
        for (int m = 0; m < 4; ++m) {
            #pragma unroll
            for (int r = 0; r < 4; ++r) {
                const int row = row0 + wr + m * 16 + fq * 4 + r;
                const float bv = bias[row];
                #pragma unroll
                for (int n = 0; n < 4; ++n) {
                    const int col = col0 + wc + n * 16 + fr;
                    O[(size_t)row * Nst + col] = f2bf(acc[m][n][r] + bv);
                }
            }
        }
    } else {
        const float sc = (which == 0) ? QSCALE : 1.0f;
        #pragma unroll
        for (int n = 0; n < 4; ++n) {
            const int col = col0 + wc + n * 16 + fr;
            const float bv = bias[col];
            #pragma unroll
            for (int m = 0; m < 4; ++m) {
                #pragma unroll
                for (int r = 0; r < 4; ++r) {
                    const int row = row0 + wr + m * 16 + fq * 4 + r;
                    O[(size_t)row * Nst + col] = f2bf((acc[m][n][r] + bv) * sc);
                }
            }
        }
    }
}

// ---------------------------------------------------------------------------
// Kernel 2: causal flash attention. 1024 blocks of 2 waves; each block owns
// the 32-row q-block PAIR (p, 31-p) -> uniform 17 k-tiles per block, so any
// block->CU assignment is load-balanced (fixes round-6 per-CU imbalance).
// 4 blocks/CU = 4 independent 2-wave barrier domains. K double-buffered in
// LDS via global_load_lds (linear dest, XOR-pre-swizzled global source;
// read applies same XOR -> conflict-free ds_read_b128). One barrier per
// k-tile. V fragments direct from global Vt (L2-hot via bh->XCD swizzle).
// ---------------------------------------------------------------------------
__global__ __launch_bounds__(128) void attn_fwd(
    const unsigned short* __restrict__ Qw, const unsigned short* __restrict__ Kw,
    const unsigned short* __restrict__ Vt, const int* __restrict__ amask,
    float* __restrict__ out)
{
    const int S = 1024, Dm = 1024;
    const int bid = blockIdx.x;
    const int bh = (bid & 7) | ((bid >> 7) << 3);   // all 16 pair-blocks of a bh -> same XCD
    const int p  = (bid >> 3) & 15;                 // pair index
    const int b = bh >> 4, h = bh & 15;
    const int t = threadIdx.x, lane = t & 63, wave = t >> 6;
    const int fr = lane & 15, fq = lane >> 4;

    __shared__ __align__(16) unsigned short Ks[2][4096];   // [64 rows][8 chunks], chunk slot j holds chunk j^(row&7)
    __shared__ __align__(16) unsigned short Ps[2][16][72];

    const size_t kwbase = (size_t)(b * S) * Dm + h * 64;
    const size_t vtbase = (size_t)(h * 64) * 4096 + b * 1024;   // Vt[d][b*S+s]

    // staging geometry: issue i covers rows [16i,16i+16); thread -> row, swizzled chunk
    const int srow_lo = t >> 3;         // 0..15
    const int schunk  = t & 7;
    const int dstoff  = wave * 512;     // u16; wave-uniform

    for (int qi = 0; qi < 2; ++qi) {
        const int qb = (qi == 0) ? p : 31 - p;      // 32-row q-block index
        const int q0 = qb * 32;
        const int nkt = (qb >> 1) + 1;              // 64-wide k-tiles

        const int qrowA = q0 + wave * 16 + fr;
        const size_t qbp = (size_t)(b * S + qrowA) * Dm + h * 64;
        const bf16x8 qf0 = *(const bf16x8*)(Qw + qbp + fq * 8);
        const bf16x8 qf1 = *(const bf16x8*)(Qw + qbp + 32 + fq * 8);

        f32x4 oacc[4] = {};
        float mrow[4], lpart[4];
        #pragma unroll
        for (int r = 0; r < 4; ++r) { mrow[r] = -3.0e38f; lpart[r] = 0.f; }

        // prologue: stage tile 0 into buf 0
        #pragma unroll
        for (int i = 0; i < 4; ++i) {
            const int r_ = 16 * i + srow_lo;
            const int cc = schunk ^ (r_ & 7);
            gload_lds16(Kw + kwbase + (size_t)r_ * Dm + cc * 8, &Ks[0][i * 1024 + dstoff]);
        }
        __syncthreads();

        int cur = 0;
        for (int kt = 0; kt < nkt; ++kt) {
            const int k0 = kt * 64;

            // stage next K tile into the other buffer (async, drains at barrier)
            if (kt + 1 < nkt) {
                #pragma unroll
                for (int i = 0; i < 4; ++i) {
                    const int r_ = 16 * i + srow_lo;
                    const int cc = schunk ^ (r_ & 7);
                    gload_lds16(Kw + kwbase + (size_t)(k0 + 64 + r_) * Dm + cc * 8,
                                &Ks[cur ^ 1][i * 1024 + dstoff]);
                }
            }

            // V fragments direct from global (issue early, consumed by PV)
            bf16x8 vb[4][2];
            #pragma unroll
            for (int d = 0; d < 4; ++d)
                #pragma unroll
                for (int kc = 0; kc < 2; ++kc)
                    vb[d][kc] = *(const bf16x8*)(Vt + vtbase + (size_t)(d * 16 + fr) * 4096 + k0 + kc * 32 + fq * 8);

            // S = Q K^T from swizzled LDS
            f32x4 sfr[4];
            __builtin_amdgcn_s_setprio(1);
            #pragma unroll
            for (int nf = 0; nf < 4; ++nf) {
                const int row = nf * 16 + fr;
                const bf16x8 kb0 = *(const bf16x8*)(&Ks[cur][row * 64 + ((fq ^ (row & 7)) * 8)]);
                const bf16x8 kb1 = *(const bf16x8*)(&Ks[cur][row * 64 + (((fq + 4) ^ (row & 7)) * 8)]);
                f32x4 z = {};
                z = __builtin_amdgcn_mfma_f32_16x16x32_bf16(qf0, kb0, z, 0, 0, 0);
                z = __builtin_amdgcn_mfma_f32_16x16x32_bf16(qf1, kb1, z, 0, 0, 0);
                sfr[nf] = z;
            }
            __builtin_amdgcn_s_setprio(0);

            // att_mask (fast path: all ones)
            const int mk = amask[b * S + k0 + lane];
            if (!__all(mk != 0)) {
                #pragma unroll
                for (int nf = 0; nf < 4; ++nf) {
                    const float pen = (amask[b * S + k0 + nf * 16 + fr] == 0) ? -3.0e38f : 0.f;
                    #pragma unroll
                    for (int r = 0; r < 4; ++r) sfr[nf][r] += pen;
                }
            }
            // causal: only diagonal tile
            if (kt == nkt - 1) {
                #pragma unroll
                for (int nf = 0; nf < 4; ++nf) {
                    const int kpos = k0 + nf * 16 + fr;
                    #pragma unroll
                    for (int r = 0; r < 4; ++r) {
                        const int qr = q0 + wave * 16 + fq * 4 + r;
                        if (kpos > qr) sfr[nf][r] = -3.0e38f;
                    }
                }
            }

            // defer-max (THR=8 in exp2 domain)
            float plm[4];
            #pragma unroll
            for (int r = 0; r < 4; ++r)
                plm[r] = fmaxf(fmaxf(sfr[0][r], sfr[1][r]), fmaxf(sfr[2][r], sfr[3][r]));
            float grow = plm[0] - mrow[0];
            #pragma unroll
            for (int r = 1; r < 4; ++r) grow = fmaxf(grow, plm[r] - mrow[r]);
            if (!__all(grow <= 8.0f)) {
                #pragma unroll
                for (int r = 0; r < 4; ++r) {
                    float v = plm[r];
                    v = fmaxf(v, __shfl_xor(v, 1));
                    v = fmaxf(v, __shfl_xor(v, 2));
                    v = fmaxf(v, __shfl_xor(v, 4));
                    v = fmaxf(v, __shfl_xor(v, 8));
                    const float mn = fmaxf(mrow[r], v);
                    const float sc = exp2f(mrow[r] - mn);
                    mrow[r] = mn;
                    lpart[r] *= sc;
                    #pragma unroll
                    for (int d = 0; d < 4; ++d) oacc[d][r] *= sc;
                }
            }

            // p = exp2(s - m); per-lane partial sums; P -> per-wave LDS (bf16)
            #pragma unroll
            for (int nf = 0; nf < 4; ++nf) {
                #pragma unroll
                for (int r = 0; r < 4; ++r) {
                    const float pv = exp2f(sfr[nf][r] - mrow[r]);
                    lpart[r] += pv;
                    Ps[wave][fq * 4 + r][nf * 16 + fr] = f2bf(pv);
                }
            }

            // O += P V
            const bf16x8 pa0 = *(const bf16x8*)(&Ps[wave][fr][fq * 8]);
            const bf16x8 pa1 = *(const bf16x8*)(&Ps[wave][fr][32 + fq * 8]);
            __builtin_amdgcn_s_setprio(1);
            #pragma unroll
            for (int d = 0; d < 4; ++d) {
                oacc[d] = __builtin_amdgcn_mfma_f32_16x16x32_bf16(pa0, vb[d][0], oacc[d], 0, 0, 0);
                oacc[d] = __builtin_amdgcn_mfma_f32_16x16x32_bf16(pa1, vb[d][1], oacc[d], 0, 0, 0);
            }
            __builtin_amdgcn_s_setprio(0);

            __syncthreads();   // drains next-tile staging; releases buffers
            cur ^= 1;
        }

        // epilogue
        float inv[4];
        #pragma unroll
        for (int r = 0; r < 4; ++r) {
            float v = lpart[r];
            v += __shfl_xor(v, 1);
            v += __shfl_xor(v, 2);
            v += __shfl_xor(v, 4);
            v += __shfl_xor(v, 8);
            inv[r] = 1.0f / v;
        }
        #pragma unroll
        for (int d = 0; d < 4; ++d)
            #pragma unroll
            for (int r = 0; r < 4; ++r) {
                const int qr = q0 + wave * 16 + fq * 4 + r;
                out[(size_t)(b * S + qr) * Dm + h * 64 + d * 16 + fr] = oacc[d][r] * inv[r];
            }
    }
}

// ---------------------------------------------------------------------------
extern "C" void kernel_launch(void* const* d_in, const int* in_sizes, int n_in,
                              void* d_out, int out_size, void* d_ws, size_t ws_size,
                              hipStream_t stream)
{
    const float* query = (const float*)d_in[0];
    const float* key_  = (const float*)d_in[1];
    const float* value = (const float*)d_in[2];
    const int*   amask = (const int*)d_in[3];
    const float* Wq = (const float*)d_in[4];
    const float* bq = (const float*)d_in[5];
    const float* Wk = (const float*)d_in[6];
    const float* bk = (const float*)d_in[7];
    const float* Wv = (const float*)d_in[8];
    const float* bv = (const float*)d_in[9];
    float* out = (float*)d_out;

    const size_t MD = (size_t)4096 * 1024;
    const size_t WD = (size_t)1024 * 1024;
    unsigned short* Qw  = (unsigned short*)d_ws;
    unsigned short* Kw  = Qw + MD;
    unsigned short* Vtw = Kw + MD;     // [1024][4096]
    unsigned short* Xq  = Vtw + MD;
    unsigned short* Xk  = Xq + MD;
    unsigned short* Xv  = Xk + MD;
    unsigned short* Wqb = Xv + MD;
    unsigned short* Wkb = Wqb + WD;
    unsigned short* Wvb = Wkb + WD;

    hipLaunchKernelGGL(cvt6, dim3(512, 6), dim3(256), 0, stream,
                       query, key_, value, Wq, Wk, Wv,
                       Xq, Xk, Xv, Wqb, Wkb, Wvb);
    // which 0: Q = Xq·Wq^T; 1: K = Xk·Wk^T; 2: Vt = Wv·Xv^T
    hipLaunchKernelGGL(gemm_bt, dim3(768), dim3(256), 0, stream,
                       Xq, Xk, Wvb, Wqb, Wkb, Xv, bq, bk, bv, Qw, Kw, Vtw);
    hipLaunchKernelGGL(attn_fwd, dim3(1024), dim3(128), 0, stream,
                       Qw, Kw, Vtw, amask, out);
}

// Round 8
// 108.161 us; speedup vs baseline: 1.5137x; 1.0591x over previous
//
#include <hip/hip_runtime.h>
#include <hip/hip_bf16.h>

using f32x4  = __attribute__((ext_vector_type(4))) float;
using bf16x8 = __attribute__((ext_vector_type(8))) __bf16;
using u16x8  = __attribute__((ext_vector_type(8))) unsigned short;

#define QSCALE 0.18033688f   // 0.125 * log2(e): scores pre-scaled into exp2 domain

static __device__ __forceinline__ unsigned short f2bf(float f) {
    unsigned u = __builtin_bit_cast(unsigned, f);
    u += 0x7FFF + ((u >> 16) & 1);   // RNE
    return (unsigned short)(u >> 16);
}

static __device__ __forceinline__ void gload_lds16(const unsigned short* g, unsigned short* l) {
    __builtin_amdgcn_global_load_lds(
        (const __attribute__((address_space(1))) unsigned int*)g,
        (__attribute__((address_space(3))) unsigned int*)l, 16, 0, 0);
}

// ---------------------------------------------------------------------------
// Kernel 0: fp32 -> bf16 convert (X q/k/v, W q/k/v).
// ---------------------------------------------------------------------------
__global__ __launch_bounds__(256) void cvt6(
    const float* __restrict__ s0, const float* __restrict__ s1, const float* __restrict__ s2,
    const float* __restrict__ s3, const float* __restrict__ s4, const float* __restrict__ s5,
    unsigned short* __restrict__ d0, unsigned short* __restrict__ d1, unsigned short* __restrict__ d2,
    unsigned short* __restrict__ d3, unsigned short* __restrict__ d4, unsigned short* __restrict__ d5)
{
    const int y = blockIdx.y;
    const float* s = y == 0 ? s0 : y == 1 ? s1 : y == 2 ? s2 : y == 3 ? s3 : y == 4 ? s4 : s5;
    unsigned short* d = y == 0 ? d0 : y == 1 ? d1 : y == 2 ? d2 : y == 3 ? d3 : y == 4 ? d4 : d5;
    const int n = (y < 3) ? 4 * 1024 * 1024 : 1024 * 1024;
    const int stride = gridDim.x * 256 * 8;
    for (int i = (blockIdx.x * 256 + threadIdx.x) * 8; i < n; i += stride) {
        f32x4 a = *(const f32x4*)(s + i);
        f32x4 b = *(const f32x4*)(s + i + 4);
        u16x8 o;
        o[0] = f2bf(a.x); o[1] = f2bf(a.y); o[2] = f2bf(a.z); o[3] = f2bf(a.w);
        o[4] = f2bf(b.x); o[5] = f2bf(b.y); o[6] = f2bf(b.z); o[7] = f2bf(b.w);
        *(u16x8*)(d + i) = o;
    }
}

// ---------------------------------------------------------------------------
// Kernel 1 (m97 structure, round-4 form): Y = X @ W^T + bias, bf16 operands.
// Uniform thin epilogue (VGPR ~68, 3 blocks/CU); which==0 (Q) ×QSCALE.
// ---------------------------------------------------------------------------
__global__ __launch_bounds__(256) void gemm_bt(
    const unsigned short* __restrict__ A0, const unsigned short* __restrict__ A1, const unsigned short* __restrict__ A2,
    const unsigned short* __restrict__ B0, const unsigned short* __restrict__ B1, const unsigned short* __restrict__ B2,
    const float* __restrict__ b0, const float* __restrict__ b1, const float* __restrict__ b2,
    unsigned short* __restrict__ O0, unsigned short* __restrict__ O1, unsigned short* __restrict__ O2)
{
    const int N = 1024, K = 1024;
    const int which = blockIdx.y;
    const unsigned short* A = which == 0 ? A0 : (which == 1 ? A1 : A2);
    const unsigned short* B = which == 0 ? B0 : (which == 1 ? B1 : B2);
    const float* bias = which == 0 ? b0 : (which == 1 ? b1 : b2);
    unsigned short* O = which == 0 ? O0 : (which == 1 ? O1 : O2);

    const int bm = blockIdx.x >> 3;
    const int bn = blockIdx.x & 7;
    const int row0 = bm * 128, col0 = bn * 128;

    __shared__ __align__(16) unsigned short As[128 * 32];
    __shared__ __align__(16) unsigned short Bs[128 * 32];

    const int t = threadIdx.x;
    const int lane = t & 63;
    const int wave = t >> 6;
    const int wr = (wave >> 1) * 64, wc = (wave & 1) * 64;
    const int fr = lane & 15;
    const int fq = lane >> 4;

    f32x4 acc[4][4] = {};

    const int r0s = t >> 2, k0s = (t & 3) * 8;
    const int r1s = (t + 256) >> 2, k1s = (t & 3) * 8;
    unsigned short* ldsA0 = &As[(wave * 64) * 8];
    unsigned short* ldsA1 = &As[(256 + wave * 64) * 8];
    unsigned short* ldsB0 = &Bs[(wave * 64) * 8];
    unsigned short* ldsB1 = &Bs[(256 + wave * 64) * 8];

    for (int k0 = 0; k0 < K; k0 += 32) {
        gload_lds16(A + (size_t)(row0 + r0s) * K + k0 + k0s, ldsA0);
        gload_lds16(A + (size_t)(row0 + r1s) * K + k0 + k1s, ldsA1);
        gload_lds16(B + (size_t)(col0 + r0s) * K + k0 + k0s, ldsB0);
        gload_lds16(B + (size_t)(col0 + r1s) * K + k0 + k1s, ldsB1);
        __syncthreads();

        bf16x8 af[4], bfr[4];
        #pragma unroll
        for (int m = 0; m < 4; ++m)
            af[m] = *(const bf16x8*)(&As[(wr + m * 16 + fr) * 32 + fq * 8]);
        #pragma unroll
        for (int n = 0; n < 4; ++n)
            bfr[n] = *(const bf16x8*)(&Bs[(wc + n * 16 + fr) * 32 + fq * 8]);
        #pragma unroll
        for (int m = 0; m < 4; ++m)
            #pragma unroll
            for (int n = 0; n < 4; ++n)
                acc[m][n] = __builtin_amdgcn_mfma_f32_16x16x32_bf16(af[m], bfr[n], acc[m][n], 0, 0, 0);
        __syncthreads();
    }

    const float sc = (which == 0) ? QSCALE : 1.0f;
    #pragma unroll
    for (int n = 0; n < 4; ++n) {
        const int col = col0 + wc + n * 16 + fr;
        const float bv = bias[col];
        #pragma unroll
        for (int m = 0; m < 4; ++m) {
            #pragma unroll
            for (int r = 0; r < 4; ++r) {
                const int row = row0 + wr + m * 16 + fq * 4 + r;
                O[(size_t)row * N + col] = f2bf((acc[m][n][r] + bv) * sc);
            }
        }
    }
}

// ---------------------------------------------------------------------------
// Kernel 1b: V[b*S+s][h*64+dk] -> Vt[(b*16+h)*64+dk][s]. LDS 64x72 tile.
// ---------------------------------------------------------------------------
__global__ __launch_bounds__(256) void vtrans(
    const unsigned short* __restrict__ V, unsigned short* __restrict__ Vt)
{
    const int S = 1024, Dm = 1024;
    const int sb = blockIdx.x;      // 16 blocks of 64 s
    const int h = blockIdx.y, b = blockIdx.z;
    __shared__ __align__(16) unsigned short Lt[64][72];   // [dk][s], padded
    const int t = threadIdx.x;

    const int sl = t >> 3, dk0 = (t & 7) * 8;
    #pragma unroll
    for (int i = 0; i < 2; ++i) {
        const int s = sl + i * 32;
        u16x8 v = *(const u16x8*)(V + (size_t)(b * S + sb * 64 + s) * Dm + h * 64 + dk0);
        #pragma unroll
        for (int j = 0; j < 8; ++j)
            Lt[dk0 + j][s] = v[j];
    }
    __syncthreads();

    const int dk = t >> 2, scc = (t & 3) * 16;
    const size_t orow = ((size_t)((b * 16 + h) * 64 + dk)) * S + sb * 64;
    *(u16x8*)(Vt + orow + scc)     = *(const u16x8*)(&Lt[dk][scc]);
    *(u16x8*)(Vt + orow + scc + 8) = *(const u16x8*)(&Lt[dk][scc + 8]);
}

// ---------------------------------------------------------------------------
// Kernel 2: causal flash attention (round-7 structure). 1024 blocks of 2
// waves; block owns q-block pair (p, 31-p) -> uniform 17 k-tiles. 4 blocks/CU
// = 4 independent 2-wave barrier domains. K double-buffered in LDS via
// global_load_lds (XOR-pre-swizzled source, same XOR on read). One barrier
// per k-tile. V fragments direct from global Vt (L2-hot via bh->XCD swizzle).
// ---------------------------------------------------------------------------
__global__ __launch_bounds__(128) void attn_fwd(
    const unsigned short* __restrict__ Qw, const unsigned short* __restrict__ Kw,
    const unsigned short* __restrict__ Vt, const int* __restrict__ amask,
    float* __restrict__ out)
{
    const int S = 1024, Dm = 1024;
    const int bid = blockIdx.x;
    const int bh = (bid & 7) | ((bid >> 7) << 3);   // all 16 pair-blocks of a bh -> same XCD
    const int p  = (bid >> 3) & 15;                 // pair index
    const int b = bh >> 4, h = bh & 15;
    const int t = threadIdx.x, lane = t & 63, wave = t >> 6;
    const int fr = lane & 15, fq = lane >> 4;

    __shared__ __align__(16) unsigned short Ks[2][4096];   // [64 rows][8 chunks], slot j holds chunk j^(row&7)
    __shared__ __align__(16) unsigned short Ps[2][16][72];

    const size_t kwbase = (size_t)(b * S) * Dm + h * 64;
    const size_t vtbase = (size_t)((b * 16 + h) * 64) * S;   // Vt[(b*16+h)*64+dk][s]

    const int srow_lo = t >> 3;         // 0..15
    const int schunk  = t & 7;
    const int dstoff  = wave * 512;     // u16; wave-uniform

    for (int qi = 0; qi < 2; ++qi) {
        const int qb = (qi == 0) ? p : 31 - p;      // 32-row q-block index
        const int q0 = qb * 32;
        const int nkt = (qb >> 1) + 1;              // 64-wide k-tiles

        const int qrowA = q0 + wave * 16 + fr;
        const size_t qbp = (size_t)(b * S + qrowA) * Dm + h * 64;
        const bf16x8 qf0 = *(const bf16x8*)(Qw + qbp + fq * 8);
        const bf16x8 qf1 = *(const bf16x8*)(Qw + qbp + 32 + fq * 8);

        f32x4 oacc[4] = {};
        float mrow[4], lpart[4];
        #pragma unroll
        for (int r = 0; r < 4; ++r) { mrow[r] = -3.0e38f; lpart[r] = 0.f; }

        // prologue: stage tile 0 into buf 0
        #pragma unroll
        for (int i = 0; i < 4; ++i) {
            const int r_ = 16 * i + srow_lo;
            const int cc = schunk ^ (r_ & 7);
            gload_lds16(Kw + kwbase + (size_t)r_ * Dm + cc * 8, &Ks[0][i * 1024 + dstoff]);
        }
        __syncthreads();

        int cur = 0;
        for (int kt = 0; kt < nkt; ++kt) {
            const int k0 = kt * 64;

            if (kt + 1 < nkt) {
                #pragma unroll
                for (int i = 0; i < 4; ++i) {
                    const int r_ = 16 * i + srow_lo;
                    const int cc = schunk ^ (r_ & 7);
                    gload_lds16(Kw + kwbase + (size_t)(k0 + 64 + r_) * Dm + cc * 8,
                                &Ks[cur ^ 1][i * 1024 + dstoff]);
                }
            }

            // V fragments direct from global (issue early, consumed by PV)
            bf16x8 vb[4][2];
            #pragma unroll
            for (int d = 0; d < 4; ++d)
                #pragma unroll
                for (int kc = 0; kc < 2; ++kc)
                    vb[d][kc] = *(const bf16x8*)(Vt + vtbase + (size_t)(d * 16 + fr) * S + k0 + kc * 32 + fq * 8);

            // S = Q K^T from swizzled LDS
            f32x4 sfr[4];
            __builtin_amdgcn_s_setprio(1);
            #pragma unroll
            for (int nf = 0; nf < 4; ++nf) {
                const int row = nf * 16 + fr;
                const bf16x8 kb0 = *(const bf16x8*)(&Ks[cur][row * 64 + ((fq ^ (row & 7)) * 8)]);
                const bf16x8 kb1 = *(const bf16x8*)(&Ks[cur][row * 64 + (((fq + 4) ^ (row & 7)) * 8)]);
                f32x4 z = {};
                z = __builtin_amdgcn_mfma_f32_16x16x32_bf16(qf0, kb0, z, 0, 0, 0);
                z = __builtin_amdgcn_mfma_f32_16x16x32_bf16(qf1, kb1, z, 0, 0, 0);
                sfr[nf] = z;
            }
            __builtin_amdgcn_s_setprio(0);

            // att_mask (fast path: all ones)
            const int mk = amask[b * S + k0 + lane];
            if (!__all(mk != 0)) {
                #pragma unroll
                for (int nf = 0; nf < 4; ++nf) {
                    const float pen = (amask[b * S + k0 + nf * 16 + fr] == 0) ? -3.0e38f : 0.f;
                    #pragma unroll
                    for (int r = 0; r < 4; ++r) sfr[nf][r] += pen;
                }
            }
            // causal: only diagonal tile
            if (kt == nkt - 1) {
                #pragma unroll
                for (int nf = 0; nf < 4; ++nf) {
                    const int kpos = k0 + nf * 16 + fr;
                    #pragma unroll
                    for (int r = 0; r < 4; ++r) {
                        const int qr = q0 + wave * 16 + fq * 4 + r;
                        if (kpos > qr) sfr[nf][r] = -3.0e38f;
                    }
                }
            }

            // defer-max (THR=8 in exp2 domain)
            float plm[4];
            #pragma unroll
            for (int r = 0; r < 4; ++r)
                plm[r] = fmaxf(fmaxf(sfr[0][r], sfr[1][r]), fmaxf(sfr[2][r], sfr[3][r]));
            float grow = plm[0] - mrow[0];
            #pragma unroll
            for (int r = 1; r < 4; ++r) grow = fmaxf(grow, plm[r] - mrow[r]);
            if (!__all(grow <= 8.0f)) {
                #pragma unroll
                for (int r = 0; r < 4; ++r) {
                    float v = plm[r];
                    v = fmaxf(v, __shfl_xor(v, 1));
                    v = fmaxf(v, __shfl_xor(v, 2));
                    v = fmaxf(v, __shfl_xor(v, 4));
                    v = fmaxf(v, __shfl_xor(v, 8));
                    const float mn = fmaxf(mrow[r], v);
                    const float sc = exp2f(mrow[r] - mn);
                    mrow[r] = mn;
                    lpart[r] *= sc;
                    #pragma unroll
                    for (int d = 0; d < 4; ++d) oacc[d][r] *= sc;
                }
            }

            // p = exp2(s - m); per-lane partial sums; P -> per-wave LDS (bf16)
            #pragma unroll
            for (int nf = 0; nf < 4; ++nf) {
                #pragma unroll
                for (int r = 0; r < 4; ++r) {
                    const float pv = exp2f(sfr[nf][r] - mrow[r]);
                    lpart[r] += pv;
                    Ps[wave][fq * 4 + r][nf * 16 + fr] = f2bf(pv);
                }
            }

            // O += P V
            const bf16x8 pa0 = *(const bf16x8*)(&Ps[wave][fr][fq * 8]);
            const bf16x8 pa1 = *(const bf16x8*)(&Ps[wave][fr][32 + fq * 8]);
            __builtin_amdgcn_s_setprio(1);
            #pragma unroll
            for (int d = 0; d < 4; ++d) {
                oacc[d] = __builtin_amdgcn_mfma_f32_16x16x32_bf16(pa0, vb[d][0], oacc[d], 0, 0, 0);
                oacc[d] = __builtin_amdgcn_mfma_f32_16x16x32_bf16(pa1, vb[d][1], oacc[d], 0, 0, 0);
            }
            __builtin_amdgcn_s_setprio(0);

            __syncthreads();   // drains next-tile staging; releases buffers
            cur ^= 1;
        }

        // epilogue
        float inv[4];
        #pragma unroll
        for (int r = 0; r < 4; ++r) {
            float v = lpart[r];
            v += __shfl_xor(v, 1);
            v += __shfl_xor(v, 2);
            v += __shfl_xor(v, 4);
            v += __shfl_xor(v, 8);
            inv[r] = 1.0f / v;
        }
        #pragma unroll
        for (int d = 0; d < 4; ++d)
            #pragma unroll
            for (int r = 0; r < 4; ++r) {
                const int qr = q0 + wave * 16 + fq * 4 + r;
                out[(size_t)(b * S + qr) * Dm + h * 64 + d * 16 + fr] = oacc[d][r] * inv[r];
            }
    }
}

// ---------------------------------------------------------------------------
extern "C" void kernel_launch(void* const* d_in, const int* in_sizes, int n_in,
                              void* d_out, int out_size, void* d_ws, size_t ws_size,
                              hipStream_t stream)
{
    const float* query = (const float*)d_in[0];
    const float* key_  = (const float*)d_in[1];
    const float* value = (const float*)d_in[2];
    const int*   amask = (const int*)d_in[3];
    const float* Wq = (const float*)d_in[4];
    const float* bq = (const float*)d_in[5];
    const float* Wk = (const float*)d_in[6];
    const float* bk = (const float*)d_in[7];
    const float* Wv = (const float*)d_in[8];
    const float* bv = (const float*)d_in[9];
    float* out = (float*)d_out;

    const size_t MD = (size_t)4096 * 1024;
    const size_t WD = (size_t)1024 * 1024;
    unsigned short* Qw  = (unsigned short*)d_ws;
    unsigned short* Kw  = Qw + MD;
    unsigned short* Vw  = Kw + MD;
    unsigned short* Vtw = Vw + MD;
    unsigned short* Xq  = Vtw + MD;
    unsigned short* Xk  = Xq + MD;
    unsigned short* Xv  = Xk + MD;
    unsigned short* Wqb = Xv + MD;
    unsigned short* Wkb = Wqb + WD;
    unsigned short* Wvb = Wkb + WD;

    hipLaunchKernelGGL(cvt6, dim3(512, 6), dim3(256), 0, stream,
                       query, key_, value, Wq, Wk, Wv,
                       Xq, Xk, Xv, Wqb, Wkb, Wvb);
    hipLaunchKernelGGL(gemm_bt, dim3(256, 3), dim3(256), 0, stream,
                       Xq, Xk, Xv, Wqb, Wkb, Wvb, bq, bk, bv, Qw, Kw, Vw);
    hipLaunchKernelGGL(vtrans, dim3(16, 16, 4), dim3(256), 0, stream, Vw, Vtw);
    hipLaunchKernelGGL(attn_fwd, dim3(1024), dim3(128), 0, stream,
                       Qw, Kw, Vtw, amask, out);
}

// Round 9
// 105.018 us; speedup vs baseline: 1.5590x; 1.0299x over previous
//
#include <hip/hip_runtime.h>
#include <hip/hip_bf16.h>

using f32x4  = __attribute__((ext_vector_type(4))) float;
using bf16x8 = __attribute__((ext_vector_type(8))) __bf16;
using u16x8  = __attribute__((ext_vector_type(8))) unsigned short;

#define QSCALE 0.18033688f   // 0.125 * log2(e): scores pre-scaled into exp2 domain

static __device__ __forceinline__ unsigned short f2bf(float f) {
    unsigned u = __builtin_bit_cast(unsigned, f);
    u += 0x7FFF + ((u >> 16) & 1);   // RNE
    return (unsigned short)(u >> 16);
}

static __device__ __forceinline__ void gload_lds16(const unsigned short* g, unsigned short* l) {
    __builtin_amdgcn_global_load_lds(
        (const __attribute__((address_space(1))) unsigned int*)g,
        (__attribute__((address_space(3))) unsigned int*)l, 16, 0, 0);
}

// ---------------------------------------------------------------------------
// Kernel 0: fp32 -> bf16 convert (X q/k/v, W q/k/v).
// ---------------------------------------------------------------------------
__global__ __launch_bounds__(256) void cvt6(
    const float* __restrict__ s0, const float* __restrict__ s1, const float* __restrict__ s2,
    const float* __restrict__ s3, const float* __restrict__ s4, const float* __restrict__ s5,
    unsigned short* __restrict__ d0, unsigned short* __restrict__ d1, unsigned short* __restrict__ d2,
    unsigned short* __restrict__ d3, unsigned short* __restrict__ d4, unsigned short* __restrict__ d5)
{
    const int y = blockIdx.y;
    const float* s = y == 0 ? s0 : y == 1 ? s1 : y == 2 ? s2 : y == 3 ? s3 : y == 4 ? s4 : s5;
    unsigned short* d = y == 0 ? d0 : y == 1 ? d1 : y == 2 ? d2 : y == 3 ? d3 : y == 4 ? d4 : d5;
    const int n = (y < 3) ? 4 * 1024 * 1024 : 1024 * 1024;
    const int stride = gridDim.x * 256 * 8;
    for (int i = (blockIdx.x * 256 + threadIdx.x) * 8; i < n; i += stride) {
        f32x4 a = *(const f32x4*)(s + i);
        f32x4 b = *(const f32x4*)(s + i + 4);
        u16x8 o;
        o[0] = f2bf(a.x); o[1] = f2bf(a.y); o[2] = f2bf(a.z); o[3] = f2bf(a.w);
        o[4] = f2bf(b.x); o[5] = f2bf(b.y); o[6] = f2bf(b.z); o[7] = f2bf(b.w);
        *(u16x8*)(d + i) = o;
    }
}

// ---------------------------------------------------------------------------
// Kernel 1 (m97 structure, round-4 form): Y = X @ W^T + bias, bf16 operands.
// Uniform thin epilogue (VGPR ~68, 3 blocks/CU); which==0 (Q) ×QSCALE.
// ---------------------------------------------------------------------------
__global__ __launch_bounds__(256) void gemm_bt(
    const unsigned short* __restrict__ A0, const unsigned short* __restrict__ A1, const unsigned short* __restrict__ A2,
    const unsigned short* __restrict__ B0, const unsigned short* __restrict__ B1, const unsigned short* __restrict__ B2,
    const float* __restrict__ b0, const float* __restrict__ b1, const float* __restrict__ b2,
    unsigned short* __restrict__ O0, unsigned short* __restrict__ O1, unsigned short* __restrict__ O2)
{
    const int N = 1024, K = 1024;
    const int which = blockIdx.y;
    const unsigned short* A = which == 0 ? A0 : (which == 1 ? A1 : A2);
    const unsigned short* B = which == 0 ? B0 : (which == 1 ? B1 : B2);
    const float* bias = which == 0 ? b0 : (which == 1 ? b1 : b2);
    unsigned short* O = which == 0 ? O0 : (which == 1 ? O1 : O2);

    const int bm = blockIdx.x >> 3;
    const int bn = blockIdx.x & 7;
    const int row0 = bm * 128, col0 = bn * 128;

    __shared__ __align__(16) unsigned short As[128 * 32];
    __shared__ __align__(16) unsigned short Bs[128 * 32];

    const int t = threadIdx.x;
    const int lane = t & 63;
    const int wave = t >> 6;
    const int wr = (wave >> 1) * 64, wc = (wave & 1) * 64;
    const int fr = lane & 15;
    const int fq = lane >> 4;

    f32x4 acc[4][4] = {};

    const int r0s = t >> 2, k0s = (t & 3) * 8;
    const int r1s = (t + 256) >> 2, k1s = (t & 3) * 8;
    unsigned short* ldsA0 = &As[(wave * 64) * 8];
    unsigned short* ldsA1 = &As[(256 + wave * 64) * 8];
    unsigned short* ldsB0 = &Bs[(wave * 64) * 8];
    unsigned short* ldsB1 = &Bs[(256 + wave * 64) * 8];

    for (int k0 = 0; k0 < K; k0 += 32) {
        gload_lds16(A + (size_t)(row0 + r0s) * K + k0 + k0s, ldsA0);
        gload_lds16(A + (size_t)(row0 + r1s) * K + k0 + k1s, ldsA1);
        gload_lds16(B + (size_t)(col0 + r0s) * K + k0 + k0s, ldsB0);
        gload_lds16(B + (size_t)(col0 + r1s) * K + k0 + k1s, ldsB1);
        __syncthreads();

        bf16x8 af[4], bfr[4];
        #pragma unroll
        for (int m = 0; m < 4; ++m)
            af[m] = *(const bf16x8*)(&As[(wr + m * 16 + fr) * 32 + fq * 8]);
        #pragma unroll
        for (int n = 0; n < 4; ++n)
            bfr[n] = *(const bf16x8*)(&Bs[(wc + n * 16 + fr) * 32 + fq * 8]);
        #pragma unroll
        for (int m = 0; m < 4; ++m)
            #pragma unroll
            for (int n = 0; n < 4; ++n)
                acc[m][n] = __builtin_amdgcn_mfma_f32_16x16x32_bf16(af[m], bfr[n], acc[m][n], 0, 0, 0);
        __syncthreads();
    }

    const float sc = (which == 0) ? QSCALE : 1.0f;
    #pragma unroll
    for (int n = 0; n < 4; ++n) {
        const int col = col0 + wc + n * 16 + fr;
        const float bv = bias[col];
        #pragma unroll
        for (int m = 0; m < 4; ++m) {
            #pragma unroll
            for (int r = 0; r < 4; ++r) {
                const int row = row0 + wr + m * 16 + fq * 4 + r;
                O[(size_t)row * N + col] = f2bf((acc[m][n][r] + bv) * sc);
            }
        }
    }
}

// ---------------------------------------------------------------------------
// Kernel 1b: V[b*S+s][h*64+dk] -> Vt[(b*16+h)*64+dk][s]. LDS 64x72 tile.
// ---------------------------------------------------------------------------
__global__ __launch_bounds__(256) void vtrans(
    const unsigned short* __restrict__ V, unsigned short* __restrict__ Vt)
{
    const int S = 1024, Dm = 1024;
    const int sb = blockIdx.x;
    const int h = blockIdx.y, b = blockIdx.z;
    __shared__ __align__(16) unsigned short Lt[64][72];
    const int t = threadIdx.x;

    const int sl = t >> 3, dk0 = (t & 7) * 8;
    #pragma unroll
    for (int i = 0; i < 2; ++i) {
        const int s = sl + i * 32;
        u16x8 v = *(const u16x8*)(V + (size_t)(b * S + sb * 64 + s) * Dm + h * 64 + dk0);
        #pragma unroll
        for (int j = 0; j < 8; ++j)
            Lt[dk0 + j][s] = v[j];
    }
    __syncthreads();

    const int dk = t >> 2, scc = (t & 3) * 16;
    const size_t orow = ((size_t)((b * 16 + h) * 64 + dk)) * S + sb * 64;
    *(u16x8*)(Vt + orow + scc)     = *(const u16x8*)(&Lt[dk][scc]);
    *(u16x8*)(Vt + orow + scc + 8) = *(const u16x8*)(&Lt[dk][scc + 8]);
}

// ---------------------------------------------------------------------------
// Kernel 2: causal flash attention. 2048 blocks x 2 waves; each block owns
// ONE 32-row q-block. bid encoding: bid&7 = bh&7 (XCD locality) and
// qb(bid+1024) = 31-qb(bid), so a CU's 8 blocks (bids spaced 256) form
// complementary pairs -> uniform per-CU load. 8 blocks/CU = 16 waves/CU.
// K double-buffered in LDS (global_load_lds, XOR-pre-swizzled source);
// Ps pad-free with XOR swizzle (col ^= (row&7)<<3) -> LDS = 20480 B exactly.
// ---------------------------------------------------------------------------
__global__ __launch_bounds__(128) void attn_fwd(
    const unsigned short* __restrict__ Qw, const unsigned short* __restrict__ Kw,
    const unsigned short* __restrict__ Vt, const int* __restrict__ amask,
    float* __restrict__ out)
{
    const int S = 1024, Dm = 1024;
    const int bid = blockIdx.x;
    const int m_  = bid >> 3;
    const int s_  = m_ >> 7;               // 0/1 half
    const int u_  = m_ & 127;
    const int p_  = u_ >> 3;               // 0..15
    const int bh  = (bid & 7) | ((u_ & 7) << 3);
    const int qb  = s_ ? (31 - p_) : p_;   // 32-row q-block index
    const int b = bh >> 4, h = bh & 15;
    const int t = threadIdx.x, lane = t & 63, wave = t >> 6;
    const int fr = lane & 15, fq = lane >> 4;

    __shared__ __align__(16) unsigned short Ks[2][4096];   // [64 rows][8 chunk slots], slot j holds chunk j^(row&7)
    __shared__ __align__(16) unsigned short Ps[2][16][64]; // XOR-swizzled: [row][col ^ ((row&7)<<3)]

    const size_t kwbase = (size_t)(b * S) * Dm + h * 64;
    const size_t vtbase = (size_t)((b * 16 + h) * 64) * S;

    const int srow_lo = t >> 3;         // 0..15
    const int schunk  = t & 7;
    const int dstoff  = wave * 512;     // u16; wave-uniform

    const int q0 = qb * 32;
    const int nkt = (qb >> 1) + 1;      // 64-wide k-tiles

    // hoisted att_mask all-ones check (bitwise & is conservative: false
    // negatives just take the exact per-tile path)
    bool mall;
    {
        const int4* ap = (const int4*)(amask + b * S);
        int acc = -1;
        #pragma unroll
        for (int c = 0; c < 4; ++c) {
            int4 v = ap[lane * 4 + c];
            acc &= (v.x != 0 && v.y != 0 && v.z != 0 && v.w != 0) ? -1 : 0;
        }
        mall = __all(acc != 0);
    }

    const int qrowA = q0 + wave * 16 + fr;
    const size_t qbp = (size_t)(b * S + qrowA) * Dm + h * 64;
    const bf16x8 qf0 = *(const bf16x8*)(Qw + qbp + fq * 8);
    const bf16x8 qf1 = *(const bf16x8*)(Qw + qbp + 32 + fq * 8);

    f32x4 oacc[4] = {};
    float mrow[4], lpart[4];
    #pragma unroll
    for (int r = 0; r < 4; ++r) { mrow[r] = -3.0e38f; lpart[r] = 0.f; }

    // prologue: stage tile 0 into buf 0
    #pragma unroll
    for (int i = 0; i < 4; ++i) {
        const int r_ = 16 * i + srow_lo;
        const int cc = schunk ^ (r_ & 7);
        gload_lds16(Kw + kwbase + (size_t)r_ * Dm + cc * 8, &Ks[0][i * 1024 + dstoff]);
    }
    __syncthreads();

    int cur = 0;
    for (int kt = 0; kt < nkt; ++kt) {
        const int k0 = kt * 64;

        if (kt + 1 < nkt) {
            #pragma unroll
            for (int i = 0; i < 4; ++i) {
                const int r_ = 16 * i + srow_lo;
                const int cc = schunk ^ (r_ & 7);
                gload_lds16(Kw + kwbase + (size_t)(k0 + 64 + r_) * Dm + cc * 8,
                            &Ks[cur ^ 1][i * 1024 + dstoff]);
            }
        }

        // V fragments direct from global (issue early, consumed by PV)
        bf16x8 vb[4][2];
        #pragma unroll
        for (int d = 0; d < 4; ++d)
            #pragma unroll
            for (int kc = 0; kc < 2; ++kc)
                vb[d][kc] = *(const bf16x8*)(Vt + vtbase + (size_t)(d * 16 + fr) * S + k0 + kc * 32 + fq * 8);

        // S = Q K^T from swizzled LDS
        f32x4 sfr[4];
        __builtin_amdgcn_s_setprio(1);
        #pragma unroll
        for (int nf = 0; nf < 4; ++nf) {
            const int row = nf * 16 + fr;
            const bf16x8 kb0 = *(const bf16x8*)(&Ks[cur][row * 64 + ((fq ^ (row & 7)) * 8)]);
            const bf16x8 kb1 = *(const bf16x8*)(&Ks[cur][row * 64 + (((fq + 4) ^ (row & 7)) * 8)]);
            f32x4 z = {};
            z = __builtin_amdgcn_mfma_f32_16x16x32_bf16(qf0, kb0, z, 0, 0, 0);
            z = __builtin_amdgcn_mfma_f32_16x16x32_bf16(qf1, kb1, z, 0, 0, 0);
            sfr[nf] = z;
        }
        __builtin_amdgcn_s_setprio(0);

        if (!mall) {
            #pragma unroll
            for (int nf = 0; nf < 4; ++nf) {
                const float pen = (amask[b * S + k0 + nf * 16 + fr] == 0) ? -3.0e38f : 0.f;
                #pragma unroll
                for (int r = 0; r < 4; ++r) sfr[nf][r] += pen;
            }
        }
        // causal: only diagonal tile
        if (kt == nkt - 1) {
            #pragma unroll
            for (int nf = 0; nf < 4; ++nf) {
                const int kpos = k0 + nf * 16 + fr;
                #pragma unroll
                for (int r = 0; r < 4; ++r) {
                    const int qr = q0 + wave * 16 + fq * 4 + r;
                    if (kpos > qr) sfr[nf][r] = -3.0e38f;
                }
            }
        }

        // defer-max (THR=8 in exp2 domain)
        float plm[4];
        #pragma unroll
        for (int r = 0; r < 4; ++r)
            plm[r] = fmaxf(fmaxf(sfr[0][r], sfr[1][r]), fmaxf(sfr[2][r], sfr[3][r]));
        float grow = plm[0] - mrow[0];
        #pragma unroll
        for (int r = 1; r < 4; ++r) grow = fmaxf(grow, plm[r] - mrow[r]);
        if (!__all(grow <= 8.0f)) {
            #pragma unroll
            for (int r = 0; r < 4; ++r) {
                float v = plm[r];
                v = fmaxf(v, __shfl_xor(v, 1));
                v = fmaxf(v, __shfl_xor(v, 2));
                v = fmaxf(v, __shfl_xor(v, 4));
                v = fmaxf(v, __shfl_xor(v, 8));
                const float mn = fmaxf(mrow[r], v);
                const float sc = exp2f(mrow[r] - mn);
                mrow[r] = mn;
                lpart[r] *= sc;
                #pragma unroll
                for (int d = 0; d < 4; ++d) oacc[d][r] *= sc;
            }
        }

        // p = exp2(s - m); per-lane partial sums; P -> swizzled LDS (bf16)
        #pragma unroll
        for (int nf = 0; nf < 4; ++nf) {
            #pragma unroll
            for (int r = 0; r < 4; ++r) {
                const float pv = exp2f(sfr[nf][r] - mrow[r]);
                lpart[r] += pv;
                const int rw = fq * 4 + r;
                const int colx = (nf * 16 + fr) ^ ((rw & 7) << 3);
                Ps[wave][rw][colx] = __builtin_bit_cast(unsigned short, (__bf16)pv);
            }
        }

        // O += P V (reads apply the same XOR)
        const bf16x8 pa0 = *(const bf16x8*)(&Ps[wave][fr][(fq ^ (fr & 7)) * 8]);
        const bf16x8 pa1 = *(const bf16x8*)(&Ps[wave][fr][((fq + 4) ^ (fr & 7)) * 8]);
        __builtin_amdgcn_s_setprio(1);
        #pragma unroll
        for (int d = 0; d < 4; ++d) {
            oacc[d] = __builtin_amdgcn_mfma_f32_16x16x32_bf16(pa0, vb[d][0], oacc[d], 0, 0, 0);
            oacc[d] = __builtin_amdgcn_mfma_f32_16x16x32_bf16(pa1, vb[d][1], oacc[d], 0, 0, 0);
        }
        __builtin_amdgcn_s_setprio(0);

        __syncthreads();   // drains next-tile staging; releases buffers
        cur ^= 1;
    }

    // epilogue
    float inv[4];
    #pragma unroll
    for (int r = 0; r < 4; ++r) {
        float v = lpart[r];
        v += __shfl_xor(v, 1);
        v += __shfl_xor(v, 2);
        v += __shfl_xor(v, 4);
        v += __shfl_xor(v, 8);
        inv[r] = 1.0f / v;
    }
    #pragma unroll
    for (int d = 0; d < 4; ++d)
        #pragma unroll
        for (int r = 0; r < 4; ++r) {
            const int qr = q0 + wave * 16 + fq * 4 + r;
            out[(size_t)(b * S + qr) * Dm + h * 64 + d * 16 + fr] = oacc[d][r] * inv[r];
        }
}

// ---------------------------------------------------------------------------
extern "C" void kernel_launch(void* const* d_in, const int* in_sizes, int n_in,
                              void* d_out, int out_size, void* d_ws, size_t ws_size,
                              hipStream_t stream)
{
    const float* query = (const float*)d_in[0];
    const float* key_  = (const float*)d_in[1];
    const float* value = (const float*)d_in[2];
    const int*   amask = (const int*)d_in[3];
    const float* Wq = (const float*)d_in[4];
    const float* bq = (const float*)d_in[5];
    const float* Wk = (const float*)d_in[6];
    const float* bk = (const float*)d_in[7];
    const float* Wv = (const float*)d_in[8];
    const float* bv = (const float*)d_in[9];
    float* out = (float*)d_out;

    const size_t MD = (size_t)4096 * 1024;
    const size_t WD = (size_t)1024 * 1024;
    unsigned short* Qw  = (unsigned short*)d_ws;
    unsigned short* Kw  = Qw + MD;
    unsigned short* Vw  = Kw + MD;
    unsigned short* Vtw = Vw + MD;
    unsigned short* Xq  = Vtw + MD;
    unsigned short* Xk  = Xq + MD;
    unsigned short* Xv  = Xk + MD;
    unsigned short* Wqb = Xv + MD;
    unsigned short* Wkb = Wqb + WD;
    unsigned short* Wvb = Wkb + WD;

    hipLaunchKernelGGL(cvt6, dim3(512, 6), dim3(256), 0, stream,
                       query, key_, value, Wq, Wk, Wv,
                       Xq, Xk, Xv, Wqb, Wkb, Wvb);
    hipLaunchKernelGGL(gemm_bt, dim3(256, 3), dim3(256), 0, stream,
                       Xq, Xk, Xv, Wqb, Wkb, Wvb, bq, bk, bv, Qw, Kw, Vw);
    hipLaunchKernelGGL(vtrans, dim3(16, 16, 4), dim3(256), 0, stream, Vw, Vtw);
    hipLaunchKernelGGL(attn_fwd, dim3(2048), dim3(128), 0, stream,
                       Qw, Kw, Vtw, amask, out);
}

// Round 10
// 96.454 us; speedup vs baseline: 1.6974x; 1.0888x over previous
//
#include <hip/hip_runtime.h>
#include <hip/hip_bf16.h>

using f32x4  = __attribute__((ext_vector_type(4))) float;
using bf16x8 = __attribute__((ext_vector_type(8))) __bf16;
using u16x8  = __attribute__((ext_vector_type(8))) unsigned short;

#define QSCALE 0.18033688f   // 0.125 * log2(e): scores pre-scaled into exp2 domain

static __device__ __forceinline__ unsigned short f2bf(float f) {
    unsigned u = __builtin_bit_cast(unsigned, f);
    u += 0x7FFF + ((u >> 16) & 1);   // RNE
    return (unsigned short)(u >> 16);
}

static __device__ __forceinline__ float fexp2(float x) {
    float r;
    asm("v_exp_f32 %0, %1" : "=v"(r) : "v"(x));
    return r;
}

static __device__ __forceinline__ void gload_lds16(const unsigned short* g, unsigned short* l) {
    __builtin_amdgcn_global_load_lds(
        (const __attribute__((address_space(1))) unsigned int*)g,
        (__attribute__((address_space(3))) unsigned int*)l, 16, 0, 0);
}

// ---------------------------------------------------------------------------
// Kernel 0: fp32 -> bf16 convert (X q/k/v, W q/k/v).
// ---------------------------------------------------------------------------
__global__ __launch_bounds__(256) void cvt6(
    const float* __restrict__ s0, const float* __restrict__ s1, const float* __restrict__ s2,
    const float* __restrict__ s3, const float* __restrict__ s4, const float* __restrict__ s5,
    unsigned short* __restrict__ d0, unsigned short* __restrict__ d1, unsigned short* __restrict__ d2,
    unsigned short* __restrict__ d3, unsigned short* __restrict__ d4, unsigned short* __restrict__ d5)
{
    const int y = blockIdx.y;
    const float* s = y == 0 ? s0 : y == 1 ? s1 : y == 2 ? s2 : y == 3 ? s3 : y == 4 ? s4 : s5;
    unsigned short* d = y == 0 ? d0 : y == 1 ? d1 : y == 2 ? d2 : y == 3 ? d3 : y == 4 ? d4 : d5;
    const int n = (y < 3) ? 4 * 1024 * 1024 : 1024 * 1024;
    const int stride = gridDim.x * 256 * 8;
    for (int i = (blockIdx.x * 256 + threadIdx.x) * 8; i < n; i += stride) {
        f32x4 a = *(const f32x4*)(s + i);
        f32x4 b = *(const f32x4*)(s + i + 4);
        u16x8 o;
        o[0] = f2bf(a.x); o[1] = f2bf(a.y); o[2] = f2bf(a.z); o[3] = f2bf(a.w);
        o[4] = f2bf(b.x); o[5] = f2bf(b.y); o[6] = f2bf(b.z); o[7] = f2bf(b.w);
        *(u16x8*)(d + i) = o;
    }
}

// ---------------------------------------------------------------------------
// Kernel 1 (m97 structure, round-4 form): Y = X @ W^T + bias, bf16 operands.
// Uniform thin epilogue (VGPR ~68, 3 blocks/CU); which==0 (Q) ×QSCALE.
// ---------------------------------------------------------------------------
__global__ __launch_bounds__(256) void gemm_bt(
    const unsigned short* __restrict__ A0, const unsigned short* __restrict__ A1, const unsigned short* __restrict__ A2,
    const unsigned short* __restrict__ B0, const unsigned short* __restrict__ B1, const unsigned short* __restrict__ B2,
    const float* __restrict__ b0, const float* __restrict__ b1, const float* __restrict__ b2,
    unsigned short* __restrict__ O0, unsigned short* __restrict__ O1, unsigned short* __restrict__ O2)
{
    const int N = 1024, K = 1024;
    const int which = blockIdx.y;
    const unsigned short* A = which == 0 ? A0 : (which == 1 ? A1 : A2);
    const unsigned short* B = which == 0 ? B0 : (which == 1 ? B1 : B2);
    const float* bias = which == 0 ? b0 : (which == 1 ? b1 : b2);
    unsigned short* O = which == 0 ? O0 : (which == 1 ? O1 : O2);

    const int bm = blockIdx.x >> 3;
    const int bn = blockIdx.x & 7;
    const int row0 = bm * 128, col0 = bn * 128;

    __shared__ __align__(16) unsigned short As[128 * 32];
    __shared__ __align__(16) unsigned short Bs[128 * 32];

    const int t = threadIdx.x;
    const int lane = t & 63;
    const int wave = t >> 6;
    const int wr = (wave >> 1) * 64, wc = (wave & 1) * 64;
    const int fr = lane & 15;
    const int fq = lane >> 4;

    f32x4 acc[4][4] = {};

    const int r0s = t >> 2, k0s = (t & 3) * 8;
    const int r1s = (t + 256) >> 2, k1s = (t & 3) * 8;
    unsigned short* ldsA0 = &As[(wave * 64) * 8];
    unsigned short* ldsA1 = &As[(256 + wave * 64) * 8];
    unsigned short* ldsB0 = &Bs[(wave * 64) * 8];
    unsigned short* ldsB1 = &Bs[(256 + wave * 64) * 8];

    for (int k0 = 0; k0 < K; k0 += 32) {
        gload_lds16(A + (size_t)(row0 + r0s) * K + k0 + k0s, ldsA0);
        gload_lds16(A + (size_t)(row0 + r1s) * K + k0 + k1s, ldsA1);
        gload_lds16(B + (size_t)(col0 + r0s) * K + k0 + k0s, ldsB0);
        gload_lds16(B + (size_t)(col0 + r1s) * K + k0 + k1s, ldsB1);
        __syncthreads();

        bf16x8 af[4], bfr[4];
        #pragma unroll
        for (int m = 0; m < 4; ++m)
            af[m] = *(const bf16x8*)(&As[(wr + m * 16 + fr) * 32 + fq * 8]);
        #pragma unroll
        for (int n = 0; n < 4; ++n)
            bfr[n] = *(const bf16x8*)(&Bs[(wc + n * 16 + fr) * 32 + fq * 8]);
        #pragma unroll
        for (int m = 0; m < 4; ++m)
            #pragma unroll
            for (int n = 0; n < 4; ++n)
                acc[m][n] = __builtin_amdgcn_mfma_f32_16x16x32_bf16(af[m], bfr[n], acc[m][n], 0, 0, 0);
        __syncthreads();
    }

    const float sc = (which == 0) ? QSCALE : 1.0f;
    #pragma unroll
    for (int n = 0; n < 4; ++n) {
        const int col = col0 + wc + n * 16 + fr;
        const float bv = bias[col];
        #pragma unroll
        for (int m = 0; m < 4; ++m) {
            #pragma unroll
            for (int r = 0; r < 4; ++r) {
                const int row = row0 + wr + m * 16 + fq * 4 + r;
                O[(size_t)row * N + col] = f2bf((acc[m][n][r] + bv) * sc);
            }
        }
    }
}

// ---------------------------------------------------------------------------
// Kernel 1b: V[b*S+s][h*64+dk] -> Vt[(b*16+h)*64+dk][s]. LDS 64x72 tile.
// ---------------------------------------------------------------------------
__global__ __launch_bounds__(256) void vtrans(
    const unsigned short* __restrict__ V, unsigned short* __restrict__ Vt)
{
    const int S = 1024, Dm = 1024;
    const int sb = blockIdx.x;
    const int h = blockIdx.y, b = blockIdx.z;
    __shared__ __align__(16) unsigned short Lt[64][72];
    const int t = threadIdx.x;

    const int sl = t >> 3, dk0 = (t & 7) * 8;
    #pragma unroll
    for (int i = 0; i < 2; ++i) {
        const int s = sl + i * 32;
        u16x8 v = *(const u16x8*)(V + (size_t)(b * S + sb * 64 + s) * Dm + h * 64 + dk0);
        #pragma unroll
        for (int j = 0; j < 8; ++j)
            Lt[dk0 + j][s] = v[j];
    }
    __syncthreads();

    const int dk = t >> 2, scc = (t & 3) * 16;
    const size_t orow = ((size_t)((b * 16 + h) * 64 + dk)) * S + sb * 64;
    *(u16x8*)(Vt + orow + scc)     = *(const u16x8*)(&Lt[dk][scc]);
    *(u16x8*)(Vt + orow + scc + 8) = *(const u16x8*)(&Lt[dk][scc + 8]);
}

// ---------------------------------------------------------------------------
// Kernel 2: causal flash attention. 2048 SINGLE-WAVE blocks (64 threads),
// each owning one 32-row q-block (wave computes 2x 16-row groups). NO
// barriers: wave-private LDS ordered by lgkm/vmcnt. K double-buffered via
// global_load_lds with counted vmcnt (never drained to 0 mid-loop, T4).
// bid encoding keeps XCD locality and complementary per-CU load balance.
// LDS = 16KiB Ks + 4KiB Ps = 20480 B -> 8 blocks/CU (all 2048 co-resident).
// ---------------------------------------------------------------------------
__global__ __launch_bounds__(64, 2) void attn_fwd(
    const unsigned short* __restrict__ Qw, const unsigned short* __restrict__ Kw,
    const unsigned short* __restrict__ Vt, const int* __restrict__ amask,
    float* __restrict__ out)
{
    const int S = 1024, Dm = 1024;
    const int bid = blockIdx.x;
    const int m_  = bid >> 3;              // 0..255
    const int s_  = m_ >> 7;
    const int u_  = m_ & 127;
    const int p_  = u_ >> 3;               // 0..15
    const int bh  = (bid & 7) | ((u_ & 7) << 3);
    const int qb  = s_ ? (31 - p_) : p_;   // 32-row q-block index
    const int b = bh >> 4, h = bh & 15;
    const int lane = threadIdx.x;
    const int fr = lane & 15, fq = lane >> 4;

    __shared__ __align__(16) unsigned short Ks[2][4096];  // [64 rows][8 chunk slots], slot j holds chunk j^(row&7)
    __shared__ __align__(16) unsigned short Ps[32][64];   // XOR-swizzled: [row][col ^ ((row&7)<<3)]

    const size_t kwbase = (size_t)(b * S) * Dm + h * 64;
    const size_t vtbase = (size_t)((b * 16 + h) * 64) * S;

    const int srow = lane >> 3;    // 0..7
    const int schunk = lane & 7;

    const int q0 = qb * 32;
    const int nkt = (qb >> 1) + 1;   // 64-wide k-tiles

    // hoisted att_mask all-ones check
    bool mall;
    {
        const int4* ap = (const int4*)(amask + b * S);
        int acc = -1;
        #pragma unroll
        for (int c = 0; c < 4; ++c) {
            int4 v = ap[lane * 4 + c];
            acc &= (v.x != 0 && v.y != 0 && v.z != 0 && v.w != 0) ? -1 : 0;
        }
        mall = __all(acc != 0);
    }

    // Q fragments: 2 row-groups x 2 k-chunks
    bf16x8 qf[2][2];
    #pragma unroll
    for (int g = 0; g < 2; ++g) {
        const size_t qbp = (size_t)(b * S + q0 + g * 16 + fr) * Dm + h * 64;
        qf[g][0] = *(const bf16x8*)(Qw + qbp + fq * 8);
        qf[g][1] = *(const bf16x8*)(Qw + qbp + 32 + fq * 8);
    }

    f32x4 oacc[2][4] = {};
    float mrow[2][4], lpart[2][4];
    #pragma unroll
    for (int g = 0; g < 2; ++g)
        #pragma unroll
        for (int r = 0; r < 4; ++r) { mrow[g][r] = -3.0e38f; lpart[g][r] = 0.f; }

    // prologue: stage tile 0 into buf 0 (8 x 1KiB issues)
    #pragma unroll
    for (int i = 0; i < 8; ++i) {
        const int r_ = 8 * i + srow;
        const int cc = schunk ^ (r_ & 7);
        gload_lds16(Kw + kwbase + (size_t)r_ * Dm + cc * 8, &Ks[0][i * 512]);
    }

    int cur = 0;
    for (int kt = 0; kt < nkt; ++kt) {
        const int k0 = kt * 64;
        const bool stage = (kt + 1 < nkt);

        // stage next K tile (async; stays in flight across this tile's compute)
        if (stage) {
            #pragma unroll
            for (int i = 0; i < 8; ++i) {
                const int r_ = 8 * i + srow;
                const int cc = schunk ^ (r_ & 7);
                gload_lds16(Kw + kwbase + (size_t)(k0 + 64 + r_) * Dm + cc * 8,
                            &Ks[cur ^ 1][i * 512]);
            }
        }

        // V fragments direct from global (issue early, consumed by PV)
        bf16x8 vb[4][2];
        #pragma unroll
        for (int d = 0; d < 4; ++d)
            #pragma unroll
            for (int kc = 0; kc < 2; ++kc)
                vb[d][kc] = *(const bf16x8*)(Vt + vtbase + (size_t)(d * 16 + fr) * S + k0 + kc * 32 + fq * 8);

        // wait: K(t) staged; K(t+1) 8 + V(t) 8 may remain in flight
        if (stage) asm volatile("s_waitcnt vmcnt(16)" ::: "memory");
        else       asm volatile("s_waitcnt vmcnt(8)"  ::: "memory");
        __builtin_amdgcn_sched_barrier(0);

        // S = Q K^T from swizzled LDS (kb fragments shared by both row-groups)
        f32x4 sfr[2][4];
        __builtin_amdgcn_s_setprio(1);
        #pragma unroll
        for (int nf = 0; nf < 4; ++nf) {
            const int row = nf * 16 + fr;
            const bf16x8 kb0 = *(const bf16x8*)(&Ks[cur][row * 64 + ((fq ^ (row & 7)) * 8)]);
            const bf16x8 kb1 = *(const bf16x8*)(&Ks[cur][row * 64 + (((fq + 4) ^ (row & 7)) * 8)]);
            #pragma unroll
            for (int g = 0; g < 2; ++g) {
                f32x4 z = {};
                z = __builtin_amdgcn_mfma_f32_16x16x32_bf16(qf[g][0], kb0, z, 0, 0, 0);
                z = __builtin_amdgcn_mfma_f32_16x16x32_bf16(qf[g][1], kb1, z, 0, 0, 0);
                sfr[g][nf] = z;
            }
        }
        __builtin_amdgcn_s_setprio(0);

        if (!mall) {
            #pragma unroll
            for (int nf = 0; nf < 4; ++nf) {
                const float pen = (amask[b * S + k0 + nf * 16 + fr] == 0) ? -3.0e38f : 0.f;
                #pragma unroll
                for (int g = 0; g < 2; ++g)
                    #pragma unroll
                    for (int r = 0; r < 4; ++r) sfr[g][nf][r] += pen;
            }
        }
        // causal: only diagonal tile
        if (kt == nkt - 1) {
            #pragma unroll
            for (int nf = 0; nf < 4; ++nf) {
                const int kpos = k0 + nf * 16 + fr;
                #pragma unroll
                for (int g = 0; g < 2; ++g)
                    #pragma unroll
                    for (int r = 0; r < 4; ++r) {
                        const int qr = q0 + g * 16 + fq * 4 + r;
                        if (kpos > qr) sfr[g][nf][r] = -3.0e38f;
                    }
            }
        }

        // defer-max (THR=8 in exp2 domain)
        float plm[2][4];
        float grow = -3.0e38f;
        #pragma unroll
        for (int g = 0; g < 2; ++g)
            #pragma unroll
            for (int r = 0; r < 4; ++r) {
                plm[g][r] = fmaxf(fmaxf(sfr[g][0][r], sfr[g][1][r]),
                                  fmaxf(sfr[g][2][r], sfr[g][3][r]));
                grow = fmaxf(grow, plm[g][r] - mrow[g][r]);
            }
        if (!__all(grow <= 8.0f)) {
            #pragma unroll
            for (int g = 0; g < 2; ++g)
                #pragma unroll
                for (int r = 0; r < 4; ++r) {
                    float v = plm[g][r];
                    v = fmaxf(v, __shfl_xor(v, 1));
                    v = fmaxf(v, __shfl_xor(v, 2));
                    v = fmaxf(v, __shfl_xor(v, 4));
                    v = fmaxf(v, __shfl_xor(v, 8));
                    const float mn = fmaxf(mrow[g][r], v);
                    const float sc = fexp2(mrow[g][r] - mn);
                    mrow[g][r] = mn;
                    lpart[g][r] *= sc;
                    #pragma unroll
                    for (int d = 0; d < 4; ++d) oacc[g][d][r] *= sc;
                }
        }

        // p = exp2(s - m); per-lane partial sums; P -> swizzled LDS (bf16)
        #pragma unroll
        for (int g = 0; g < 2; ++g)
            #pragma unroll
            for (int nf = 0; nf < 4; ++nf)
                #pragma unroll
                for (int r = 0; r < 4; ++r) {
                    const float pv = fexp2(sfr[g][nf][r] - mrow[g][r]);
                    lpart[g][r] += pv;
                    const int rw = g * 16 + fq * 4 + r;
                    const int colx = (nf * 16 + fr) ^ ((rw & 7) << 3);
                    Ps[rw][colx] = f2bf(pv);
                }

        // O += P V (reads apply the same XOR; lgkm ordering is wave-local)
        __builtin_amdgcn_s_setprio(1);
        #pragma unroll
        for (int g = 0; g < 2; ++g) {
            const bf16x8 pa0 = *(const bf16x8*)(&Ps[g * 16 + fr][(fq ^ (fr & 7)) * 8]);
            const bf16x8 pa1 = *(const bf16x8*)(&Ps[g * 16 + fr][((fq + 4) ^ (fr & 7)) * 8]);
            #pragma unroll
            for (int d = 0; d < 4; ++d) {
                oacc[g][d] = __builtin_amdgcn_mfma_f32_16x16x32_bf16(pa0, vb[d][0], oacc[g][d], 0, 0, 0);
                oacc[g][d] = __builtin_amdgcn_mfma_f32_16x16x32_bf16(pa1, vb[d][1], oacc[g][d], 0, 0, 0);
            }
        }
        __builtin_amdgcn_s_setprio(0);

        cur ^= 1;
    }

    // epilogue
    #pragma unroll
    for (int g = 0; g < 2; ++g) {
        float inv[4];
        #pragma unroll
        for (int r = 0; r < 4; ++r) {
            float v = lpart[g][r];
            v += __shfl_xor(v, 1);
            v += __shfl_xor(v, 2);
            v += __shfl_xor(v, 4);
            v += __shfl_xor(v, 8);
            inv[r] = 1.0f / v;
        }
        #pragma unroll
        for (int d = 0; d < 4; ++d)
            #pragma unroll
            for (int r = 0; r < 4; ++r) {
                const int qr = q0 + g * 16 + fq * 4 + r;
                out[(size_t)(b * S + qr) * Dm + h * 64 + d * 16 + fr] = oacc[g][d][r] * inv[r];
            }
    }
}

// ---------------------------------------------------------------------------
extern "C" void kernel_launch(void* const* d_in, const int* in_sizes, int n_in,
                              void* d_out, int out_size, void* d_ws, size_t ws_size,
                              hipStream_t stream)
{
    const float* query = (const float*)d_in[0];
    const float* key_  = (const float*)d_in[1];
    const float* value = (const float*)d_in[2];
    const int*   amask = (const int*)d_in[3];
    const float* Wq = (const float*)d_in[4];
    const float* bq = (const float*)d_in[5];
    const float* Wk = (const float*)d_in[6];
    const float* bk = (const float*)d_in[7];
    const float* Wv = (const float*)d_in[8];
    const float* bv = (const float*)d_in[9];
    float* out = (float*)d_out;

    const size_t MD = (size_t)4096 * 1024;
    const size_t WD = (size_t)1024 * 1024;
    unsigned short* Qw  = (unsigned short*)d_ws;
    unsigned short* Kw  = Qw + MD;
    unsigned short* Vw  = Kw + MD;
    unsigned short* Vtw = Vw + MD;
    unsigned short* Xq  = Vtw + MD;
    unsigned short* Xk  = Xq + MD;
    unsigned short* Xv  = Xk + MD;
    unsigned short* Wqb = Xv + MD;
    unsigned short* Wkb = Wqb + WD;
    unsigned short* Wvb = Wkb + WD;

    hipLaunchKernelGGL(cvt6, dim3(512, 6), dim3(256), 0, stream,
                       query, key_, value, Wq, Wk, Wv,
                       Xq, Xk, Xv, Wqb, Wkb, Wvb);
    hipLaunchKernelGGL(gemm_bt, dim3(256, 3), dim3(256), 0, stream,
                       Xq, Xk, Xv, Wqb, Wkb, Wvb, bq, bk, bv, Qw, Kw, Vw);
    hipLaunchKernelGGL(vtrans, dim3(16, 16, 4), dim3(256), 0, stream, Vw, Vtw);
    hipLaunchKernelGGL(attn_fwd, dim3(2048), dim3(64), 0, stream,
                       Qw, Kw, Vtw, amask, out);
}

// Round 11
// 92.325 us; speedup vs baseline: 1.7733x; 1.0447x over previous
//
#include <hip/hip_runtime.h>
#include <hip/hip_bf16.h>

using f32x4  = __attribute__((ext_vector_type(4))) float;
using bf16x8 = __attribute__((ext_vector_type(8))) __bf16;
using u16x8  = __attribute__((ext_vector_type(8))) unsigned short;

#define QSCALE 0.18033688f   // 0.125 * log2(e): scores pre-scaled into exp2 domain

static __device__ __forceinline__ unsigned short f2bf(float f) {
    unsigned u = __builtin_bit_cast(unsigned, f);
    u += 0x7FFF + ((u >> 16) & 1);   // RNE
    return (unsigned short)(u >> 16);
}

static __device__ __forceinline__ float fexp2(float x) {
    float r;
    asm("v_exp_f32 %0, %1" : "=v"(r) : "v"(x));
    return r;
}

static __device__ __forceinline__ void gload_lds16(const unsigned short* g, unsigned short* l) {
    __builtin_amdgcn_global_load_lds(
        (const __attribute__((address_space(1))) unsigned int*)g,
        (__attribute__((address_space(3))) unsigned int*)l, 16, 0, 0);
}

// ---------------------------------------------------------------------------
// Kernel 0: fp32 -> bf16 convert (X q/k/v, W q/k/v).
// ---------------------------------------------------------------------------
__global__ __launch_bounds__(256) void cvt6(
    const float* __restrict__ s0, const float* __restrict__ s1, const float* __restrict__ s2,
    const float* __restrict__ s3, const float* __restrict__ s4, const float* __restrict__ s5,
    unsigned short* __restrict__ d0, unsigned short* __restrict__ d1, unsigned short* __restrict__ d2,
    unsigned short* __restrict__ d3, unsigned short* __restrict__ d4, unsigned short* __restrict__ d5)
{
    const int y = blockIdx.y;
    const float* s = y == 0 ? s0 : y == 1 ? s1 : y == 2 ? s2 : y == 3 ? s3 : y == 4 ? s4 : s5;
    unsigned short* d = y == 0 ? d0 : y == 1 ? d1 : y == 2 ? d2 : y == 3 ? d3 : y == 4 ? d4 : d5;
    const int n = (y < 3) ? 4 * 1024 * 1024 : 1024 * 1024;
    const int stride = gridDim.x * 256 * 8;
    for (int i = (blockIdx.x * 256 + threadIdx.x) * 8; i < n; i += stride) {
        f32x4 a = *(const f32x4*)(s + i);
        f32x4 b = *(const f32x4*)(s + i + 4);
        u16x8 o;
        o[0] = f2bf(a.x); o[1] = f2bf(a.y); o[2] = f2bf(a.z); o[3] = f2bf(a.w);
        o[4] = f2bf(b.x); o[5] = f2bf(b.y); o[6] = f2bf(b.z); o[7] = f2bf(b.w);
        *(u16x8*)(d + i) = o;
    }
}

// ---------------------------------------------------------------------------
// Kernel 1 (m97 structure): Y = X @ W^T + bias, bf16 operands.
// XCD-chunked swizzle: x' = (x&7)*32 + x>>3, so XCD k (= x%8 under
// round-robin dispatch) owns bm in [4k,4k+4) x all bn -> each A row-panel
// is fetched by exactly ONE XCD's L2 (cuts cross-XCD A over-fetch 8x).
// Uniform thin epilogue; which==0 (Q) xQSCALE.
// ---------------------------------------------------------------------------
__global__ __launch_bounds__(256) void gemm_bt(
    const unsigned short* __restrict__ A0, const unsigned short* __restrict__ A1, const unsigned short* __restrict__ A2,
    const unsigned short* __restrict__ B0, const unsigned short* __restrict__ B1, const unsigned short* __restrict__ B2,
    const float* __restrict__ b0, const float* __restrict__ b1, const float* __restrict__ b2,
    unsigned short* __restrict__ O0, unsigned short* __restrict__ O1, unsigned short* __restrict__ O2)
{
    const int N = 1024, K = 1024;
    const int which = blockIdx.y;
    const unsigned short* A = which == 0 ? A0 : (which == 1 ? A1 : A2);
    const unsigned short* B = which == 0 ? B0 : (which == 1 ? B1 : B2);
    const float* bias = which == 0 ? b0 : (which == 1 ? b1 : b2);
    unsigned short* O = which == 0 ? O0 : (which == 1 ? O1 : O2);

    const int xs = (blockIdx.x & 7) * 32 + (blockIdx.x >> 3);   // bijective XCD chunking
    const int bm = xs >> 3;
    const int bn = xs & 7;
    const int row0 = bm * 128, col0 = bn * 128;

    __shared__ __align__(16) unsigned short As[128 * 32];
    __shared__ __align__(16) unsigned short Bs[128 * 32];

    const int t = threadIdx.x;
    const int lane = t & 63;
    const int wave = t >> 6;
    const int wr = (wave >> 1) * 64, wc = (wave & 1) * 64;
    const int fr = lane & 15;
    const int fq = lane >> 4;

    f32x4 acc[4][4] = {};

    const int r0s = t >> 2, k0s = (t & 3) * 8;
    const int r1s = (t + 256) >> 2, k1s = (t & 3) * 8;
    unsigned short* ldsA0 = &As[(wave * 64) * 8];
    unsigned short* ldsA1 = &As[(256 + wave * 64) * 8];
    unsigned short* ldsB0 = &Bs[(wave * 64) * 8];
    unsigned short* ldsB1 = &Bs[(256 + wave * 64) * 8];

    for (int k0 = 0; k0 < K; k0 += 32) {
        gload_lds16(A + (size_t)(row0 + r0s) * K + k0 + k0s, ldsA0);
        gload_lds16(A + (size_t)(row0 + r1s) * K + k0 + k1s, ldsA1);
        gload_lds16(B + (size_t)(col0 + r0s) * K + k0 + k0s, ldsB0);
        gload_lds16(B + (size_t)(col0 + r1s) * K + k0 + k1s, ldsB1);
        __syncthreads();

        bf16x8 af[4], bfr[4];
        #pragma unroll
        for (int m = 0; m < 4; ++m)
            af[m] = *(const bf16x8*)(&As[(wr + m * 16 + fr) * 32 + fq * 8]);
        #pragma unroll
        for (int n = 0; n < 4; ++n)
            bfr[n] = *(const bf16x8*)(&Bs[(wc + n * 16 + fr) * 32 + fq * 8]);
        #pragma unroll
        for (int m = 0; m < 4; ++m)
            #pragma unroll
            for (int n = 0; n < 4; ++n)
                acc[m][n] = __builtin_amdgcn_mfma_f32_16x16x32_bf16(af[m], bfr[n], acc[m][n], 0, 0, 0);
        __syncthreads();
    }

    const float sc = (which == 0) ? QSCALE : 1.0f;
    #pragma unroll
    for (int n = 0; n < 4; ++n) {
        const int col = col0 + wc + n * 16 + fr;
        const float bv = bias[col];
        #pragma unroll
        for (int m = 0; m < 4; ++m) {
            #pragma unroll
            for (int r = 0; r < 4; ++r) {
                const int row = row0 + wr + m * 16 + fq * 4 + r;
                O[(size_t)row * N + col] = f2bf((acc[m][n][r] + bv) * sc);
            }
        }
    }
}

// ---------------------------------------------------------------------------
// Kernel 1b: V[b*S+s][h*64+dk] -> Vt[(b*16+h)*64+dk][s]. LDS 64x72 tile.
// ---------------------------------------------------------------------------
__global__ __launch_bounds__(256) void vtrans(
    const unsigned short* __restrict__ V, unsigned short* __restrict__ Vt)
{
    const int S = 1024, Dm = 1024;
    const int sb = blockIdx.x;
    const int h = blockIdx.y, b = blockIdx.z;
    __shared__ __align__(16) unsigned short Lt[64][72];
    const int t = threadIdx.x;

    const int sl = t >> 3, dk0 = (t & 7) * 8;
    #pragma unroll
    for (int i = 0; i < 2; ++i) {
        const int s = sl + i * 32;
        u16x8 v = *(const u16x8*)(V + (size_t)(b * S + sb * 64 + s) * Dm + h * 64 + dk0);
        #pragma unroll
        for (int j = 0; j < 8; ++j)
            Lt[dk0 + j][s] = v[j];
    }
    __syncthreads();

    const int dk = t >> 2, scc = (t & 3) * 16;
    const size_t orow = ((size_t)((b * 16 + h) * 64 + dk)) * S + sb * 64;
    *(u16x8*)(Vt + orow + scc)     = *(const u16x8*)(&Lt[dk][scc]);
    *(u16x8*)(Vt + orow + scc + 8) = *(const u16x8*)(&Lt[dk][scc + 8]);
}

// ---------------------------------------------------------------------------
// Kernel 2: causal flash attention. 2048 SINGLE-WAVE blocks (64 threads),
// each owning one 32-row q-block (wave computes 2x 16-row groups). NO
// barriers: wave-private LDS ordered by lgkm/vmcnt. K double-buffered via
// global_load_lds with counted vmcnt (never drained to 0 mid-loop, T4).
// bid encoding keeps XCD locality and complementary per-CU load balance.
// LDS = 16KiB Ks + 4KiB Ps = 20480 B -> 8 blocks/CU (all 2048 co-resident).
// ---------------------------------------------------------------------------
__global__ __launch_bounds__(64, 2) void attn_fwd(
    const unsigned short* __restrict__ Qw, const unsigned short* __restrict__ Kw,
    const unsigned short* __restrict__ Vt, const int* __restrict__ amask,
    float* __restrict__ out)
{
    const int S = 1024, Dm = 1024;
    const int bid = blockIdx.x;
    const int m_  = bid >> 3;              // 0..255
    const int s_  = m_ >> 7;
    const int u_  = m_ & 127;
    const int p_  = u_ >> 3;               // 0..15
    const int bh  = (bid & 7) | ((u_ & 7) << 3);
    const int qb  = s_ ? (31 - p_) : p_;   // 32-row q-block index
    const int b = bh >> 4, h = bh & 15;
    const int lane = threadIdx.x;
    const int fr = lane & 15, fq = lane >> 4;

    __shared__ __align__(16) unsigned short Ks[2][4096];  // [64 rows][8 chunk slots], slot j holds chunk j^(row&7)
    __shared__ __align__(16) unsigned short Ps[32][64];   // XOR-swizzled: [row][col ^ ((row&7)<<3)]

    const size_t kwbase = (size_t)(b * S) * Dm + h * 64;
    const size_t vtbase = (size_t)((b * 16 + h) * 64) * S;

    const int srow = lane >> 3;    // 0..7
    const int schunk = lane & 7;

    const int q0 = qb * 32;
    const int nkt = (qb >> 1) + 1;   // 64-wide k-tiles

    // hoisted att_mask all-ones check
    bool mall;
    {
        const int4* ap = (const int4*)(amask + b * S);
        int acc = -1;
        #pragma unroll
        for (int c = 0; c < 4; ++c) {
            int4 v = ap[lane * 4 + c];
            acc &= (v.x != 0 && v.y != 0 && v.z != 0 && v.w != 0) ? -1 : 0;
        }
        mall = __all(acc != 0);
    }

    // Q fragments: 2 row-groups x 2 k-chunks
    bf16x8 qf[2][2];
    #pragma unroll
    for (int g = 0; g < 2; ++g) {
        const size_t qbp = (size_t)(b * S + q0 + g * 16 + fr) * Dm + h * 64;
        qf[g][0] = *(const bf16x8*)(Qw + qbp + fq * 8);
        qf[g][1] = *(const bf16x8*)(Qw + qbp + 32 + fq * 8);
    }

    f32x4 oacc[2][4] = {};
    float mrow[2][4], lpart[2][4];
    #pragma unroll
    for (int g = 0; g < 2; ++g)
        #pragma unroll
        for (int r = 0; r < 4; ++r) { mrow[g][r] = -3.0e38f; lpart[g][r] = 0.f; }

    // prologue: stage tile 0 into buf 0 (8 x 1KiB issues)
    #pragma unroll
    for (int i = 0; i < 8; ++i) {
        const int r_ = 8 * i + srow;
        const int cc = schunk ^ (r_ & 7);
        gload_lds16(Kw + kwbase + (size_t)r_ * Dm + cc * 8, &Ks[0][i * 512]);
    }

    int cur = 0;
    for (int kt = 0; kt < nkt; ++kt) {
        const int k0 = kt * 64;
        const bool stage = (kt + 1 < nkt);

        // stage next K tile (async; stays in flight across this tile's compute)
        if (stage) {
            #pragma unroll
            for (int i = 0; i < 8; ++i) {
                const int r_ = 8 * i + srow;
                const int cc = schunk ^ (r_ & 7);
                gload_lds16(Kw + kwbase + (size_t)(k0 + 64 + r_) * Dm + cc * 8,
                            &Ks[cur ^ 1][i * 512]);
            }
        }

        // V fragments direct from global (issue early, consumed by PV)
        bf16x8 vb[4][2];
        #pragma unroll
        for (int d = 0; d < 4; ++d)
            #pragma unroll
            for (int kc = 0; kc < 2; ++kc)
                vb[d][kc] = *(const bf16x8*)(Vt + vtbase + (size_t)(d * 16 + fr) * S + k0 + kc * 32 + fq * 8);

        // wait: K(t) staged; K(t+1) 8 + V(t) 8 may remain in flight
        if (stage) asm volatile("s_waitcnt vmcnt(16)" ::: "memory");
        else       asm volatile("s_waitcnt vmcnt(8)"  ::: "memory");
        __builtin_amdgcn_sched_barrier(0);

        // S = Q K^T from swizzled LDS (kb fragments shared by both row-groups)
        f32x4 sfr[2][4];
        __builtin_amdgcn_s_setprio(1);
        #pragma unroll
        for (int nf = 0; nf < 4; ++nf) {
            const int row = nf * 16 + fr;
            const bf16x8 kb0 = *(const bf16x8*)(&Ks[cur][row * 64 + ((fq ^ (row & 7)) * 8)]);
            const bf16x8 kb1 = *(const bf16x8*)(&Ks[cur][row * 64 + (((fq + 4) ^ (row & 7)) * 8)]);
            #pragma unroll
            for (int g = 0; g < 2; ++g) {
                f32x4 z = {};
                z = __builtin_amdgcn_mfma_f32_16x16x32_bf16(qf[g][0], kb0, z, 0, 0, 0);
                z = __builtin_amdgcn_mfma_f32_16x16x32_bf16(qf[g][1], kb1, z, 0, 0, 0);
                sfr[g][nf] = z;
            }
        }
        __builtin_amdgcn_s_setprio(0);

        if (!mall) {
            #pragma unroll
            for (int nf = 0; nf < 4; ++nf) {
                const float pen = (amask[b * S + k0 + nf * 16 + fr] == 0) ? -3.0e38f : 0.f;
                #pragma unroll
                for (int g = 0; g < 2; ++g)
                    #pragma unroll
                    for (int r = 0; r < 4; ++r) sfr[g][nf][r] += pen;
            }
        }
        // causal: only diagonal tile
        if (kt == nkt - 1) {
            #pragma unroll
            for (int nf = 0; nf < 4; ++nf) {
                const int kpos = k0 + nf * 16 + fr;
                #pragma unroll
                for (int g = 0; g < 2; ++g)
                    #pragma unroll
                    for (int r = 0; r < 4; ++r) {
                        const int qr = q0 + g * 16 + fq * 4 + r;
                        if (kpos > qr) sfr[g][nf][r] = -3.0e38f;
                    }
            }
        }

        // defer-max (THR=8 in exp2 domain)
        float plm[2][4];
        float grow = -3.0e38f;
        #pragma unroll
        for (int g = 0; g < 2; ++g)
            #pragma unroll
            for (int r = 0; r < 4; ++r) {
                plm[g][r] = fmaxf(fmaxf(sfr[g][0][r], sfr[g][1][r]),
                                  fmaxf(sfr[g][2][r], sfr[g][3][r]));
                grow = fmaxf(grow, plm[g][r] - mrow[g][r]);
            }
        if (!__all(grow <= 8.0f)) {
            #pragma unroll
            for (int g = 0; g < 2; ++g)
                #pragma unroll
                for (int r = 0; r < 4; ++r) {
                    float v = plm[g][r];
                    v = fmaxf(v, __shfl_xor(v, 1));
                    v = fmaxf(v, __shfl_xor(v, 2));
                    v = fmaxf(v, __shfl_xor(v, 4));
                    v = fmaxf(v, __shfl_xor(v, 8));
                    const float mn = fmaxf(mrow[g][r], v);
                    const float sc = fexp2(mrow[g][r] - mn);
                    mrow[g][r] = mn;
                    lpart[g][r] *= sc;
                    #pragma unroll
                    for (int d = 0; d < 4; ++d) oacc[g][d][r] *= sc;
                }
        }

        // p = exp2(s - m); per-lane partial sums; P -> swizzled LDS (bf16)
        #pragma unroll
        for (int g = 0; g < 2; ++g)
            #pragma unroll
            for (int nf = 0; nf < 4; ++nf)
                #pragma unroll
                for (int r = 0; r < 4; ++r) {
                    const float pv = fexp2(sfr[g][nf][r] - mrow[g][r]);
                    lpart[g][r] += pv;
                    const int rw = g * 16 + fq * 4 + r;
                    const int colx = (nf * 16 + fr) ^ ((rw & 7) << 3);
                    Ps[rw][colx] = f2bf(pv);
                }

        // O += P V (reads apply the same XOR; lgkm ordering is wave-local)
        __builtin_amdgcn_s_setprio(1);
        #pragma unroll
        for (int g = 0; g < 2; ++g) {
            const bf16x8 pa0 = *(const bf16x8*)(&Ps[g * 16 + fr][(fq ^ (fr & 7)) * 8]);
            const bf16x8 pa1 = *(const bf16x8*)(&Ps[g * 16 + fr][((fq + 4) ^ (fr & 7)) * 8]);
            #pragma unroll
            for (int d = 0; d < 4; ++d) {
                oacc[g][d] = __builtin_amdgcn_mfma_f32_16x16x32_bf16(pa0, vb[d][0], oacc[g][d], 0, 0, 0);
                oacc[g][d] = __builtin_amdgcn_mfma_f32_16x16x32_bf16(pa1, vb[d][1], oacc[g][d], 0, 0, 0);
            }
        }
        __builtin_amdgcn_s_setprio(0);

        cur ^= 1;
    }

    // epilogue
    #pragma unroll
    for (int g = 0; g < 2; ++g) {
        float inv[4];
        #pragma unroll
        for (int r = 0; r < 4; ++r) {
            float v = lpart[g][r];
            v += __shfl_xor(v, 1);
            v += __shfl_xor(v, 2);
            v += __shfl_xor(v, 4);
            v += __shfl_xor(v, 8);
            inv[r] = 1.0f / v;
        }
        #pragma unroll
        for (int d = 0; d < 4; ++d)
            #pragma unroll
            for (int r = 0; r < 4; ++r) {
                const int qr = q0 + g * 16 + fq * 4 + r;
                out[(size_t)(b * S + qr) * Dm + h * 64 + d * 16 + fr] = oacc[g][d][r] * inv[r];
            }
    }
}

// ---------------------------------------------------------------------------
extern "C" void kernel_launch(void* const* d_in, const int* in_sizes, int n_in,
                              void* d_out, int out_size, void* d_ws, size_t ws_size,
                              hipStream_t stream)
{
    const float* query = (const float*)d_in[0];
    const float* key_  = (const float*)d_in[1];
    const float* value = (const float*)d_in[2];
    const int*   amask = (const int*)d_in[3];
    const float* Wq = (const float*)d_in[4];
    const float* bq = (const float*)d_in[5];
    const float* Wk = (const float*)d_in[6];
    const float* bk = (const float*)d_in[7];
    const float* Wv = (const float*)d_in[8];
    const float* bv = (const float*)d_in[9];
    float* out = (float*)d_out;

    const size_t MD = (size_t)4096 * 1024;
    const size_t WD = (size_t)1024 * 1024;
    unsigned short* Qw  = (unsigned short*)d_ws;
    unsigned short* Kw  = Qw + MD;
    unsigned short* Vw  = Kw + MD;
    unsigned short* Vtw = Vw + MD;
    unsigned short* Xq  = Vtw + MD;
    unsigned short* Xk  = Xq + MD;
    unsigned short* Xv  = Xk + MD;
    unsigned short* Wqb = Xv + MD;
    unsigned short* Wkb = Wqb + WD;
    unsigned short* Wvb = Wkb + WD;

    hipLaunchKernelGGL(cvt6, dim3(512, 6), dim3(256), 0, stream,
                       query, key_, value, Wq, Wk, Wv,
                       Xq, Xk, Xv, Wqb, Wkb, Wvb);
    hipLaunchKernelGGL(gemm_bt, dim3(256, 3), dim3(256), 0, stream,
                       Xq, Xk, Xv, Wqb, Wkb, Wvb, bq, bk, bv, Qw, Kw, Vw);
    hipLaunchKernelGGL(vtrans, dim3(16, 16, 4), dim3(256), 0, stream, Vw, Vtw);
    hipLaunchKernelGGL(attn_fwd, dim3(2048), dim3(64), 0, stream,
                       Qw, Kw, Vtw, amask, out);
}